// Round 1
// baseline (408.344 us; speedup 1.0000x reference)
//
#include <hip/hip_runtime.h>
#include <hip/hip_bf16.h>
#include <stdint.h>
#include <stddef.h>

typedef __attribute__((ext_vector_type(8))) short bf16x8;       // MFMA A/B frag (8 bf16)
typedef __attribute__((ext_vector_type(8))) unsigned short u16x8;
typedef __attribute__((ext_vector_type(4))) float f32x4;        // MFMA C/D frag

#define TT 1024
#define QKV_N 6144

__device__ __forceinline__ unsigned short f2bf(float f){
  unsigned u = __builtin_bit_cast(unsigned, f);
  unsigned r = 0x7fffu + ((u >> 16) & 1u);
  return (unsigned short)((u + r) >> 16);
}
__device__ __forceinline__ float bf2f(unsigned short s){
  unsigned u = ((unsigned)s) << 16;
  return __builtin_bit_cast(float, u);
}

// ---------------- cast x (fp32 -> bf16), 4 elems/thread ----------------
__global__ void cast_x_kernel(const float* __restrict__ in, unsigned short* __restrict__ out){
  int i = blockIdx.x * 256 + threadIdx.x;
  float4 v = reinterpret_cast<const float4*>(in)[i];
  ushort4 o;
  o.x = f2bf(v.x); o.y = f2bf(v.y); o.z = f2bf(v.z); o.w = f2bf(v.w);
  reinterpret_cast<ushort4*>(out)[i] = o;
}

// ---------------- transpose + cast: in [R][C] fp32 -> out [C][R] bf16 ----------------
__global__ void transpose_cast_kernel(const float* __restrict__ in, unsigned short* __restrict__ out,
                                      int R, int C){
  __shared__ float tile[32][33];
  int c0 = blockIdx.x * 32, r0 = blockIdx.y * 32;
  for (int i = threadIdx.y; i < 32; i += 8)
    tile[i][threadIdx.x] = in[(size_t)(r0 + i) * C + c0 + threadIdx.x];
  __syncthreads();
  for (int i = threadIdx.y; i < 32; i += 8)
    out[(size_t)(c0 + i) * R + r0 + threadIdx.x] = f2bf(tile[threadIdx.x][i]);
}

// ---------------- router: logits, softmax, top-4 gate (fp32) ----------------
__global__ void router_kernel(const float* __restrict__ x, const float* __restrict__ wr,
                              float* __restrict__ gate){
  int t = blockIdx.x;
  int lane = threadIdx.x;           // 64
  int h = lane & 31, half = lane >> 5;
  const float* xr = x + (size_t)t * 2048 + half * 1024;
  const float* wp = wr + (size_t)half * 1024 * 32 + h;
  float acc = 0.f;
  #pragma unroll 4
  for (int k = 0; k < 1024; k++) acc += xr[k] * wp[k * 32];
  float other = __shfl_down(acc, 32);
  acc += other;                      // lanes 0..31 hold full logit for head h
  float logit = (lane < 32) ? acc : -3.4e38f;

  // softmax over 32 heads (lanes 0..31; xor masks <=16 stay within group)
  float m = logit;
  #pragma unroll
  for (int s = 16; s >= 1; s >>= 1) m = fmaxf(m, __shfl_xor(m, s));
  float e = __expf(logit - m);
  float sum = e;
  #pragma unroll
  for (int s = 16; s >= 1; s >>= 1) sum += __shfl_xor(sum, s);
  float prob = e / sum;

  // top-4 by logit (same order as prob); ties -> lowest index (matches lax.top_k)
  float v = logit;
  int sel = 0;
  #pragma unroll
  for (int rr = 0; rr < 4; rr++){
    float bv = v; int bi = h;
    #pragma unroll
    for (int s = 16; s >= 1; s >>= 1){
      float ov = __shfl_xor(bv, s); int oi = __shfl_xor(bi, s);
      if (ov > bv || (ov == bv && oi < bi)) { bv = ov; bi = oi; }
    }
    if (h == bi && lane < 32) { sel = 1; v = -3.4e38f; }
  }
  if (lane < 32) gate[(size_t)t * 32 + h] = sel ? prob : 0.f;
}

// ---------------- RoPE cos/sin table: tab[pos][i] = {cos, sin} ----------------
__global__ void rope_table_kernel(float* __restrict__ tab){
  int idx = blockIdx.x * 256 + threadIdx.x;   // 1024*32
  int pos = idx >> 5, i = idx & 31;
  float freq = powf(10000.0f, -(float)i / 32.0f);
  float ang = (float)pos * freq;
  tab[idx * 2]     = cosf(ang);
  tab[idx * 2 + 1] = sinf(ang);
}

// ---------------- RoPE in-place on q,k sections of qkv (cols 0..4096) ----------------
__global__ void rope_apply_kernel(unsigned short* __restrict__ qkv, const float* __restrict__ tab){
  int idx = blockIdx.x * 256 + threadIdx.x;   // 4096 * 512
  int t = idx >> 9;
  int cc = (idx & 511) * 8;                   // col in [0,4096), multiple of 8
  int pos = t & (TT - 1);
  int i0 = (cc & 63) >> 1;                    // starting pair index
  unsigned short* p = qkv + (size_t)t * QKV_N + cc;
  u16x8 v = *(const u16x8*)p;
  const float* tp = tab + ((size_t)pos * 32 + i0) * 2;
  #pragma unroll
  for (int j = 0; j < 4; j++){
    float c = tp[j * 2], s = tp[j * 2 + 1];
    float a = bf2f(v[2 * j]), b = bf2f(v[2 * j + 1]);
    v[2 * j]     = f2bf(a * c - b * s);
    v[2 * j + 1] = f2bf(a * s + b * c);
  }
  *(u16x8*)p = v;
}

// ---------------- V transpose: qkv v-section -> vt[bh*64+d][1024] ----------------
__global__ void transpose_v_kernel(const unsigned short* __restrict__ qkv,
                                   unsigned short* __restrict__ vt){
  __shared__ unsigned short tile[64][72];     // 144B row stride (16B aligned)
  int bh = blockIdx.x, tt = blockIdx.y;
  int b = bh >> 5, h = bh & 31;
  int tid = threadIdx.x;
  #pragma unroll
  for (int s2 = 0; s2 < 2; s2++){
    int s = s2 * 256 + tid;
    int r = s >> 3, c = (s & 7) * 8;
    u16x8 v = *(const u16x8*)(qkv + (size_t)(b * TT + tt * 64 + r) * QKV_N + 4096 + h * 64 + c);
    *(u16x8*)(&tile[r][c]) = v;
  }
  __syncthreads();
  #pragma unroll
  for (int s2 = 0; s2 < 2; s2++){
    int s = s2 * 256 + tid;
    int d = s >> 3, c = (s & 7) * 8;
    u16x8 v;
    #pragma unroll
    for (int j = 0; j < 8; j++) v[j] = tile[c + j][d];
    *(u16x8*)(vt + (size_t)(bh * 64 + d) * TT + tt * 64 + c) = v;
  }
}

// ---------------- bf16 MFMA GEMM: C[M][N] = A[M][K] * Bt[N][K]^T ----------------
template<bool BF16_OUT>
__global__ __launch_bounds__(256) void gemm_bt(const unsigned short* __restrict__ A,
                                               const unsigned short* __restrict__ Bt,
                                               void* __restrict__ Cv,
                                               int M, int N, int K){
  __shared__ unsigned short As[128 * 32];
  __shared__ unsigned short Bs[128 * 32];
  const int bn = blockIdx.x, bm = blockIdx.y;
  const int tid = threadIdx.x, lane = tid & 63, wid = tid >> 6;
  const int wr = wid >> 1, wc = wid & 1;
  const int li = lane & 15, lg = lane >> 4;
  f32x4 acc[4][4];
  #pragma unroll
  for (int i = 0; i < 4; i++)
    #pragma unroll
    for (int j = 0; j < 4; j++) acc[i][j] = f32x4{0.f, 0.f, 0.f, 0.f};

  for (int k0 = 0; k0 < K; k0 += 32){
    #pragma unroll
    for (int rr = 0; rr < 2; rr++){
      int slot = rr * 256 + tid;
      int row = slot >> 2, co = (slot & 3) * 8;
      bf16x8 va = *(const bf16x8*)(A  + (size_t)(bm * 128 + row) * K + k0 + co);
      bf16x8 vb = *(const bf16x8*)(Bt + (size_t)(bn * 128 + row) * K + k0 + co);
      *(bf16x8*)(&As[row * 32 + co]) = va;
      *(bf16x8*)(&Bs[row * 32 + co]) = vb;
    }
    __syncthreads();
    bf16x8 af[4], bfr[4];
    #pragma unroll
    for (int i = 0; i < 4; i++){
      af[i]  = *(const bf16x8*)(&As[(wr * 64 + i * 16 + li) * 32 + lg * 8]);
      bfr[i] = *(const bf16x8*)(&Bs[(wc * 64 + i * 16 + li) * 32 + lg * 8]);
    }
    #pragma unroll
    for (int i = 0; i < 4; i++)
      #pragma unroll
      for (int j = 0; j < 4; j++)
        acc[i][j] = __builtin_amdgcn_mfma_f32_16x16x32_bf16(af[i], bfr[j], acc[i][j], 0, 0, 0);
    __syncthreads();
  }
  // epilogue: C row = (lane>>4)*4 + reg, col = lane&15  [verified layout]
  #pragma unroll
  for (int i = 0; i < 4; i++){
    #pragma unroll
    for (int j = 0; j < 4; j++){
      #pragma unroll
      for (int r = 0; r < 4; r++){
        size_t row = (size_t)(bm * 128 + wr * 64 + i * 16 + lg * 4 + r);
        size_t col = (size_t)(bn * 128 + wc * 64 + j * 16 + li);
        if (BF16_OUT) ((unsigned short*)Cv)[row * N + col] = f2bf(acc[i][j][r]);
        else          ((float*)Cv)[row * N + col] = acc[i][j][r];
      }
    }
  }
}

// ---------------- flash attention per (b,h,q-tile64), gate in epilogue ----------------
__global__ __launch_bounds__(256) void attn_kernel(const unsigned short* __restrict__ qkv,
                                                   const unsigned short* __restrict__ vt,
                                                   const float* __restrict__ gate,
                                                   unsigned short* __restrict__ attn_out){
  __shared__ unsigned short Ks[64 * 64];      // [k][d]
  __shared__ unsigned short Vs[64 * 64];      // V^T: [d][k]
  __shared__ unsigned short Ps[4][16 * 64];   // per-wave P: [q][k]
  const int bh = blockIdx.x, qt = blockIdx.y;
  const int b = bh >> 5, h = bh & 31;
  const int tid = threadIdx.x, lane = tid & 63, w = tid >> 6;
  const int li = lane & 15, lg = lane >> 4;
  const int qbase = qt * 64 + w * 16;

  // Q fragments (roped) straight from global
  bf16x8 qf0, qf1;
  {
    const unsigned short* qp = qkv + (size_t)(b * TT + qbase + li) * QKV_N + h * 64;
    qf0 = *(const bf16x8*)(qp + lg * 8);
    qf1 = *(const bf16x8*)(qp + 32 + lg * 8);
  }
  f32x4 o[4];
  #pragma unroll
  for (int i = 0; i < 4; i++) o[i] = f32x4{0.f, 0.f, 0.f, 0.f};
  float m_run[4], l_run[4];
  #pragma unroll
  for (int r = 0; r < 4; r++){ m_run[r] = -1e30f; l_run[r] = 0.f; }

  for (int kt = 0; kt <= qt; kt++){
    const int kb = kt * 64;
    #pragma unroll
    for (int s2 = 0; s2 < 2; s2++){
      int s = s2 * 256 + tid;
      int r = s >> 3, c = (s & 7) * 8;
      *(u16x8*)(&Ks[r * 64 + c]) =
          *(const u16x8*)(qkv + (size_t)(b * TT + kb + r) * QKV_N + 2048 + h * 64 + c);
      *(u16x8*)(&Vs[r * 64 + c]) =
          *(const u16x8*)(vt + (size_t)(bh * 64 + r) * TT + kb + c);
    }
    __syncthreads();

    // S = Q K^T
    f32x4 s4[4];
    #pragma unroll
    for (int ni = 0; ni < 4; ni++){
      bf16x8 k0 = *(const bf16x8*)(&Ks[(ni * 16 + li) * 64 + lg * 8]);
      bf16x8 k1 = *(const bf16x8*)(&Ks[(ni * 16 + li) * 64 + 32 + lg * 8]);
      f32x4 t = f32x4{0.f, 0.f, 0.f, 0.f};
      t = __builtin_amdgcn_mfma_f32_16x16x32_bf16(qf0, k0, t, 0, 0, 0);
      t = __builtin_amdgcn_mfma_f32_16x16x32_bf16(qf1, k1, t, 0, 0, 0);
      s4[ni] = t;
    }
    // scale + causal mask + tile row max
    float mt[4];
    #pragma unroll
    for (int r = 0; r < 4; r++) mt[r] = -1e30f;
    #pragma unroll
    for (int ni = 0; ni < 4; ni++){
      int kidx = kb + ni * 16 + li;
      #pragma unroll
      for (int r = 0; r < 4; r++){
        int qi = qbase + lg * 4 + r;
        float val = s4[ni][r] * 0.125f;
        val = (kidx <= qi) ? val : -1e30f;
        s4[ni][r] = val;
        mt[r] = fmaxf(mt[r], val);
      }
    }
    // online softmax update
    #pragma unroll
    for (int r = 0; r < 4; r++){
      #pragma unroll
      for (int sh = 8; sh >= 1; sh >>= 1) mt[r] = fmaxf(mt[r], __shfl_xor(mt[r], sh));
      float mnew = fmaxf(m_run[r], mt[r]);
      float corr = __expf(m_run[r] - mnew);
      m_run[r] = mnew;
      l_run[r] *= corr;
      #pragma unroll
      for (int j = 0; j < 4; j++) o[j][r] *= corr;
    }
    float rs[4] = {0.f, 0.f, 0.f, 0.f};
    #pragma unroll
    for (int ni = 0; ni < 4; ni++)
      #pragma unroll
      for (int r = 0; r < 4; r++){
        float p = __expf(s4[ni][r] - m_run[r]);
        s4[ni][r] = p;
        rs[r] += p;
      }
    #pragma unroll
    for (int r = 0; r < 4; r++){
      #pragma unroll
      for (int sh = 8; sh >= 1; sh >>= 1) rs[r] += __shfl_xor(rs[r], sh);
      l_run[r] += rs[r];
    }
    // P -> LDS (bf16), then PV
    #pragma unroll
    for (int ni = 0; ni < 4; ni++)
      #pragma unroll
      for (int r = 0; r < 4; r++)
        Ps[w][(lg * 4 + r) * 64 + ni * 16 + li] = f2bf(s4[ni][r]);
    #pragma unroll
    for (int ks = 0; ks < 2; ks++){
      bf16x8 pa = *(const bf16x8*)(&Ps[w][li * 64 + ks * 32 + lg * 8]);
      #pragma unroll
      for (int ni = 0; ni < 4; ni++){
        bf16x8 vb = *(const bf16x8*)(&Vs[(ni * 16 + li) * 64 + ks * 32 + lg * 8]);
        o[ni] = __builtin_amdgcn_mfma_f32_16x16x32_bf16(pa, vb, o[ni], 0, 0, 0);
      }
    }
    __syncthreads();
  }
  // epilogue: gate * O / l
  #pragma unroll
  for (int r = 0; r < 4; r++){
    int qi = qbase + lg * 4 + r;
    float g = gate[(size_t)(b * TT + qi) * 32 + h];
    float inv = g / l_run[r];
    #pragma unroll
    for (int ni = 0; ni < 4; ni++)
      attn_out[(size_t)(b * TT + qi) * 2048 + h * 64 + ni * 16 + li] = f2bf(o[ni][r] * inv);
  }
}

extern "C" void kernel_launch(void* const* d_in, const int* in_sizes, int n_in,
                              void* d_out, int out_size, void* d_ws, size_t ws_size,
                              hipStream_t stream){
  const float* x        = (const float*)d_in[0];
  const float* w_router = (const float*)d_in[1];
  const float* w_qkv    = (const float*)d_in[2];
  const float* w_out    = (const float*)d_in[3];
  float* out = (float*)d_out;
  char* ws = (char*)d_ws;

  unsigned short* qkv   = (unsigned short*)(ws);                        // 50331648 B
  unsigned short* x_bf  = (unsigned short*)(ws + 50331648);             // 16777216 B
  unsigned short* wqkvT = (unsigned short*)(ws + 50331648 + 16777216);  // 25165824 B
  unsigned short* woutT = (unsigned short*)(ws + 92274688);             // 8388608 B
  float* gate           = (float*)(ws + 100663296);                     // 524288 B
  float* tab            = (float*)(ws + 101187584);                     // 262144 B
  unsigned short* attn  = x_bf;    // reuse: x_bf dead after qkv GEMM
  unsigned short* vt    = wqkvT;   // reuse: wqkvT dead after qkv GEMM

  hipLaunchKernelGGL(cast_x_kernel, dim3(8192), dim3(256), 0, stream, x, x_bf);
  hipLaunchKernelGGL(transpose_cast_kernel, dim3(192, 64), dim3(32, 8), 0, stream, w_qkv, wqkvT, 2048, 6144);
  hipLaunchKernelGGL(transpose_cast_kernel, dim3(64, 64), dim3(32, 8), 0, stream, w_out, woutT, 2048, 2048);
  hipLaunchKernelGGL(router_kernel, dim3(4096), dim3(64), 0, stream, x, w_router, gate);
  hipLaunchKernelGGL(rope_table_kernel, dim3(128), dim3(256), 0, stream, tab);
  hipLaunchKernelGGL(gemm_bt<true>, dim3(48, 32), dim3(256), 0, stream, x_bf, wqkvT, (void*)qkv, 4096, 6144, 2048);
  hipLaunchKernelGGL(rope_apply_kernel, dim3(8192), dim3(256), 0, stream, qkv, tab);
  hipLaunchKernelGGL(transpose_v_kernel, dim3(128, 16), dim3(256), 0, stream, qkv, vt);
  hipLaunchKernelGGL(attn_kernel, dim3(128, 16), dim3(256), 0, stream, qkv, vt, gate, attn);
  hipLaunchKernelGGL(gemm_bt<false>, dim3(16, 32), dim3(256), 0, stream, attn, woutT, (void*)out, 4096, 2048, 2048);
}

// Round 2
// 367.449 us; speedup vs baseline: 1.1113x; 1.1113x over previous
//
#include <hip/hip_runtime.h>
#include <hip/hip_bf16.h>
#include <stdint.h>
#include <stddef.h>

typedef __attribute__((ext_vector_type(8))) short bf16x8;       // MFMA A/B frag (8 bf16)
typedef __attribute__((ext_vector_type(8))) unsigned short u16x8;
typedef __attribute__((ext_vector_type(4))) float f32x4;        // MFMA C/D frag

#define TT 1024
#define QKV_N 6144

__device__ __forceinline__ unsigned short f2bf(float f){
  unsigned u = __builtin_bit_cast(unsigned, f);
  unsigned r = 0x7fffu + ((u >> 16) & 1u);
  return (unsigned short)((u + r) >> 16);
}
__device__ __forceinline__ float bf2f(unsigned short s){
  unsigned u = ((unsigned)s) << 16;
  return __builtin_bit_cast(float, u);
}
// async global->LDS, 16B per lane. LDS dest must be firstlane-base + lane*16 (tid-linear).
__device__ __forceinline__ void gload16(const unsigned short* g, unsigned short* l){
  __builtin_amdgcn_global_load_lds(
      (const __attribute__((address_space(1))) void*)g,
      (__attribute__((address_space(3))) void*)l, 16, 0, 0);
}

// ---------------- cast x (fp32 -> bf16), 4 elems/thread ----------------
__global__ void cast_x_kernel(const float* __restrict__ in, unsigned short* __restrict__ out){
  int i = blockIdx.x * 256 + threadIdx.x;
  float4 v = reinterpret_cast<const float4*>(in)[i];
  ushort4 o;
  o.x = f2bf(v.x); o.y = f2bf(v.y); o.z = f2bf(v.z); o.w = f2bf(v.w);
  reinterpret_cast<ushort4*>(out)[i] = o;
}

// ---------------- transpose + cast: in [R][C] fp32 -> out [C][R] bf16 ----------------
__global__ void transpose_cast_kernel(const float* __restrict__ in, unsigned short* __restrict__ out,
                                      int R, int C){
  __shared__ float tile[32][33];
  int c0 = blockIdx.x * 32, r0 = blockIdx.y * 32;
  for (int i = threadIdx.y; i < 32; i += 8)
    tile[i][threadIdx.x] = in[(size_t)(r0 + i) * C + c0 + threadIdx.x];
  __syncthreads();
  for (int i = threadIdx.y; i < 32; i += 8)
    out[(size_t)(c0 + i) * R + r0 + threadIdx.x] = f2bf(tile[threadIdx.x][i]);
}

// ---------------- router: logits, softmax, top-4 gate (fp32) ----------------
__global__ void router_kernel(const float* __restrict__ x, const float* __restrict__ wr,
                              float* __restrict__ gate){
  int t = blockIdx.x;
  int lane = threadIdx.x;           // 64
  int h = lane & 31, half = lane >> 5;
  const float* xr = x + (size_t)t * 2048 + half * 1024;
  const float* wp = wr + (size_t)half * 1024 * 32 + h;
  float acc = 0.f;
  #pragma unroll 4
  for (int k = 0; k < 1024; k++) acc += xr[k] * wp[k * 32];
  float other = __shfl_down(acc, 32);
  acc += other;                      // lanes 0..31 hold full logit for head h
  float logit = (lane < 32) ? acc : -3.4e38f;

  float m = logit;
  #pragma unroll
  for (int s = 16; s >= 1; s >>= 1) m = fmaxf(m, __shfl_xor(m, s));
  float e = __expf(logit - m);
  float sum = e;
  #pragma unroll
  for (int s = 16; s >= 1; s >>= 1) sum += __shfl_xor(sum, s);
  float prob = e / sum;

  // top-4 by logit; ties -> lowest index (matches lax.top_k)
  float v = logit;
  int sel = 0;
  #pragma unroll
  for (int rr = 0; rr < 4; rr++){
    float bv = v; int bi = h;
    #pragma unroll
    for (int s = 16; s >= 1; s >>= 1){
      float ov = __shfl_xor(bv, s); int oi = __shfl_xor(bi, s);
      if (ov > bv || (ov == bv && oi < bi)) { bv = ov; bi = oi; }
    }
    if (h == bi && lane < 32) { sel = 1; v = -3.4e38f; }
  }
  if (lane < 32) gate[(size_t)t * 32 + h] = sel ? prob : 0.f;
}

// ---------------- RoPE cos/sin table ----------------
__global__ void rope_table_kernel(float* __restrict__ tab){
  int idx = blockIdx.x * 256 + threadIdx.x;   // 1024*32
  int pos = idx >> 5, i = idx & 31;
  float freq = powf(10000.0f, -(float)i / 32.0f);
  float ang = (float)pos * freq;
  tab[idx * 2]     = cosf(ang);
  tab[idx * 2 + 1] = sinf(ang);
}

// ---------------- RoPE in-place on q,k sections of qkv ----------------
__global__ void rope_apply_kernel(unsigned short* __restrict__ qkv, const float* __restrict__ tab){
  int idx = blockIdx.x * 256 + threadIdx.x;   // 4096 * 512
  int t = idx >> 9;
  int cc = (idx & 511) * 8;
  int pos = t & (TT - 1);
  int i0 = (cc & 63) >> 1;
  unsigned short* p = qkv + (size_t)t * QKV_N + cc;
  u16x8 v = *(const u16x8*)p;
  const float* tp = tab + ((size_t)pos * 32 + i0) * 2;
  #pragma unroll
  for (int j = 0; j < 4; j++){
    float c = tp[j * 2], s = tp[j * 2 + 1];
    float a = bf2f(v[2 * j]), b = bf2f(v[2 * j + 1]);
    v[2 * j]     = f2bf(a * c - b * s);
    v[2 * j + 1] = f2bf(a * s + b * c);
  }
  *(u16x8*)p = v;
}

// ---------------- V transpose: qkv v-section -> vt[bh*64+d][1024] ----------------
__global__ void transpose_v_kernel(const unsigned short* __restrict__ qkv,
                                   unsigned short* __restrict__ vt){
  __shared__ unsigned short tile[64][72];
  int bh = blockIdx.x, tt = blockIdx.y;
  int b = bh >> 5, h = bh & 31;
  int tid = threadIdx.x;
  #pragma unroll
  for (int s2 = 0; s2 < 2; s2++){
    int s = s2 * 256 + tid;
    int r = s >> 3, c = (s & 7) * 8;
    u16x8 v = *(const u16x8*)(qkv + (size_t)(b * TT + tt * 64 + r) * QKV_N + 4096 + h * 64 + c);
    *(u16x8*)(&tile[r][c]) = v;
  }
  __syncthreads();
  #pragma unroll
  for (int s2 = 0; s2 < 2; s2++){
    int s = s2 * 256 + tid;
    int d = s >> 3, c = (s & 7) * 8;
    u16x8 v;
    #pragma unroll
    for (int j = 0; j < 8; j++) v[j] = tile[c + j][d];
    *(u16x8*)(vt + (size_t)(bh * 64 + d) * TT + tt * 64 + c) = v;
  }
}

// ---------------- per-(b,h) active-token compaction (order-preserving) ----------------
__global__ void compact_kernel(const float* __restrict__ gate, int* __restrict__ idx,
                               int* __restrict__ counts){
  int bh = blockIdx.x;               // 0..127
  int b = bh >> 5, h = bh & 31;
  int lane = threadIdx.x;            // 64
  int base = 0;
  for (int c = 0; c < 16; c++){
    int t = c * 64 + lane;
    bool act = gate[(size_t)(b * TT + t) * 32 + h] != 0.f;
    unsigned long long mask = __ballot(act);
    int pos = base + __popcll(mask & ((1ull << lane) - 1ull));
    if (act) idx[bh * TT + pos] = t;
    base += __popcll(mask);
  }
  if (lane == 0) counts[bh] = base;
}

// ---------------- bf16 MFMA GEMM (m97-style global_load_lds staging) ----------------
template<bool BF16_OUT>
__global__ __launch_bounds__(256) void gemm_bt(const unsigned short* __restrict__ A,
                                               const unsigned short* __restrict__ Bt,
                                               void* __restrict__ Cv,
                                               int M, int N, int K){
  __shared__ unsigned short As[128 * 32];
  __shared__ unsigned short Bs[128 * 32];
  const int bn = blockIdx.x, bm = blockIdx.y;
  const int tid = threadIdx.x, lane = tid & 63, wid = tid >> 6;
  const int wr = wid >> 1, wc = wid & 1;
  const int li = lane & 15, lg = lane >> 4;
  f32x4 acc[4][4];
  #pragma unroll
  for (int i = 0; i < 4; i++)
    #pragma unroll
    for (int j = 0; j < 4; j++) acc[i][j] = f32x4{0.f, 0.f, 0.f, 0.f};

  for (int k0 = 0; k0 < K; k0 += 32){
    #pragma unroll
    for (int rr = 0; rr < 2; rr++){
      int slot = rr * 256 + tid;
      int row = slot >> 2, co = (slot & 3) * 8;   // row*32+co == slot*8 (tid-linear LDS)
      gload16(A  + (size_t)(bm * 128 + row) * K + k0 + co, &As[slot * 8]);
      gload16(Bt + (size_t)(bn * 128 + row) * K + k0 + co, &Bs[slot * 8]);
    }
    __syncthreads();
    bf16x8 af[4], bfr[4];
    #pragma unroll
    for (int i = 0; i < 4; i++){
      af[i]  = *(const bf16x8*)(&As[(wr * 64 + i * 16 + li) * 32 + lg * 8]);
      bfr[i] = *(const bf16x8*)(&Bs[(wc * 64 + i * 16 + li) * 32 + lg * 8]);
    }
    #pragma unroll
    for (int i = 0; i < 4; i++)
      #pragma unroll
      for (int j = 0; j < 4; j++)
        acc[i][j] = __builtin_amdgcn_mfma_f32_16x16x32_bf16(af[i], bfr[j], acc[i][j], 0, 0, 0);
    __syncthreads();
  }
  #pragma unroll
  for (int i = 0; i < 4; i++){
    #pragma unroll
    for (int j = 0; j < 4; j++){
      #pragma unroll
      for (int r = 0; r < 4; r++){
        size_t row = (size_t)(bm * 128 + wr * 64 + i * 16 + lg * 4 + r);
        size_t col = (size_t)(bn * 128 + wc * 64 + j * 16 + li);
        if (BF16_OUT) ((unsigned short*)Cv)[row * N + col] = f2bf(acc[i][j][r]);
        else          ((float*)Cv)[row * N + col] = acc[i][j][r];
      }
    }
  }
}

// ---------------- sparse flash attention over gathered active q rows ----------------
__global__ __launch_bounds__(256) void attn_sparse_kernel(const unsigned short* __restrict__ qkv,
                                                          const unsigned short* __restrict__ vt,
                                                          const float* __restrict__ gate,
                                                          const int* __restrict__ idx,
                                                          const int* __restrict__ counts,
                                                          unsigned short* __restrict__ attn_out){
  __shared__ unsigned short Ks[64 * 64];      // [k][d]
  __shared__ unsigned short Vs[64 * 64];      // V^T: [d][k]
  __shared__ unsigned short Ps[4][16 * 64];   // per-wave P: [q][k]
  const int bh = blockIdx.x, qt = blockIdx.y;
  const int count = counts[bh];
  if (qt * 64 >= count) return;
  const int b = bh >> 5, h = bh & 31;
  const int tid = threadIdx.x, lane = tid & 63, w = tid >> 6;
  const int li = lane & 15, lg = lane >> 4;
  const int* myidx = idx + bh * TT + qt * 64;
  const int nvalid = min(64, count - qt * 64);
  const int qmax = myidx[nvalid - 1];         // sorted ascending

  // actual q index per output row (lg*4+r within this wave's 16 rows)
  int qi[4];
  #pragma unroll
  for (int r = 0; r < 4; r++){
    int s = w * 16 + lg * 4 + r;
    qi[r] = (s < nvalid) ? myidx[s] : -1;
  }
  // Q fragment rows (A-operand row = li within wave's 16)
  int qrow = (w * 16 + li < nvalid) ? myidx[w * 16 + li] : 0;
  bf16x8 qf0, qf1;
  {
    const unsigned short* qp = qkv + (size_t)(b * TT + qrow) * QKV_N + h * 64;
    qf0 = *(const bf16x8*)(qp + lg * 8);
    qf1 = *(const bf16x8*)(qp + 32 + lg * 8);
  }
  f32x4 o[4];
  #pragma unroll
  for (int i = 0; i < 4; i++) o[i] = f32x4{0.f, 0.f, 0.f, 0.f};
  float m_run[4], l_run[4];
  #pragma unroll
  for (int r = 0; r < 4; r++){ m_run[r] = -1e30f; l_run[r] = 0.f; }

  const int nkt = (qmax >> 6) + 1;
  for (int kt = 0; kt < nkt; kt++){
    const int kb = kt * 64;
    #pragma unroll
    for (int s2 = 0; s2 < 2; s2++){
      int s = s2 * 256 + tid;
      int r = s >> 3, c = (s & 7) * 8;       // r*64+c == s*8 (tid-linear LDS)
      gload16(qkv + (size_t)(b * TT + kb + r) * QKV_N + 2048 + h * 64 + c, &Ks[s * 8]);
      gload16(vt + (size_t)(bh * 64 + r) * TT + kb + c, &Vs[s * 8]);
    }
    __syncthreads();

    f32x4 s4[4];
    #pragma unroll
    for (int ni = 0; ni < 4; ni++){
      bf16x8 k0 = *(const bf16x8*)(&Ks[(ni * 16 + li) * 64 + lg * 8]);
      bf16x8 k1 = *(const bf16x8*)(&Ks[(ni * 16 + li) * 64 + 32 + lg * 8]);
      f32x4 t = f32x4{0.f, 0.f, 0.f, 0.f};
      t = __builtin_amdgcn_mfma_f32_16x16x32_bf16(qf0, k0, t, 0, 0, 0);
      t = __builtin_amdgcn_mfma_f32_16x16x32_bf16(qf1, k1, t, 0, 0, 0);
      s4[ni] = t;
    }
    float mt[4];
    #pragma unroll
    for (int r = 0; r < 4; r++) mt[r] = -1e30f;
    #pragma unroll
    for (int ni = 0; ni < 4; ni++){
      int kidx = kb + ni * 16 + li;
      #pragma unroll
      for (int r = 0; r < 4; r++){
        float val = s4[ni][r] * 0.125f;
        val = (kidx <= qi[r]) ? val : -1e30f;
        s4[ni][r] = val;
        mt[r] = fmaxf(mt[r], val);
      }
    }
    #pragma unroll
    for (int r = 0; r < 4; r++){
      #pragma unroll
      for (int sh = 8; sh >= 1; sh >>= 1) mt[r] = fmaxf(mt[r], __shfl_xor(mt[r], sh));
      float mnew = fmaxf(m_run[r], mt[r]);
      float corr = __expf(m_run[r] - mnew);
      m_run[r] = mnew;
      l_run[r] *= corr;
      #pragma unroll
      for (int j = 0; j < 4; j++) o[j][r] *= corr;
    }
    float rs[4] = {0.f, 0.f, 0.f, 0.f};
    #pragma unroll
    for (int ni = 0; ni < 4; ni++)
      #pragma unroll
      for (int r = 0; r < 4; r++){
        float p = __expf(s4[ni][r] - m_run[r]);
        s4[ni][r] = p;
        rs[r] += p;
      }
    #pragma unroll
    for (int r = 0; r < 4; r++){
      #pragma unroll
      for (int sh = 8; sh >= 1; sh >>= 1) rs[r] += __shfl_xor(rs[r], sh);
      l_run[r] += rs[r];
    }
    #pragma unroll
    for (int ni = 0; ni < 4; ni++)
      #pragma unroll
      for (int r = 0; r < 4; r++)
        Ps[w][(lg * 4 + r) * 64 + ni * 16 + li] = f2bf(s4[ni][r]);
    #pragma unroll
    for (int ks = 0; ks < 2; ks++){
      bf16x8 pa = *(const bf16x8*)(&Ps[w][li * 64 + ks * 32 + lg * 8]);
      #pragma unroll
      for (int ni = 0; ni < 4; ni++){
        bf16x8 vb = *(const bf16x8*)(&Vs[(ni * 16 + li) * 64 + ks * 32 + lg * 8]);
        o[ni] = __builtin_amdgcn_mfma_f32_16x16x32_bf16(pa, vb, o[ni], 0, 0, 0);
      }
    }
    __syncthreads();
  }
  // epilogue: gate * O / l, only real rows
  #pragma unroll
  for (int r = 0; r < 4; r++){
    if (qi[r] < 0) continue;
    float g = gate[(size_t)(b * TT + qi[r]) * 32 + h];
    float inv = g / l_run[r];
    #pragma unroll
    for (int ni = 0; ni < 4; ni++)
      attn_out[(size_t)(b * TT + qi[r]) * 2048 + h * 64 + ni * 16 + li] = f2bf(o[ni][r] * inv);
  }
}

extern "C" void kernel_launch(void* const* d_in, const int* in_sizes, int n_in,
                              void* d_out, int out_size, void* d_ws, size_t ws_size,
                              hipStream_t stream){
  const float* x        = (const float*)d_in[0];
  const float* w_router = (const float*)d_in[1];
  const float* w_qkv    = (const float*)d_in[2];
  const float* w_out    = (const float*)d_in[3];
  float* out = (float*)d_out;
  char* ws = (char*)d_ws;

  unsigned short* qkv   = (unsigned short*)(ws);                        // 50331648 B
  unsigned short* x_bf  = (unsigned short*)(ws + 50331648);             // 16777216 B
  unsigned short* wqkvT = (unsigned short*)(ws + 67108864);             // 25165824 B
  unsigned short* woutT = (unsigned short*)(ws + 92274688);             // 8388608 B
  float* gate           = (float*)(ws + 100663296);                     // 524288 B
  float* tab            = (float*)(ws + 101187584);                     // 262144 B
  unsigned short* attn  = x_bf;                      // reuse after qkv GEMM
  unsigned short* vt    = wqkvT;                     // reuse after qkv GEMM (16.8 MB)
  int* idx              = (int*)(ws + 83886080);     // in wqkvT region, after vt
  int* counts           = (int*)(ws + 84410368);

  hipLaunchKernelGGL(cast_x_kernel, dim3(8192), dim3(256), 0, stream, x, x_bf);
  hipLaunchKernelGGL(transpose_cast_kernel, dim3(192, 64), dim3(32, 8), 0, stream, w_qkv, wqkvT, 2048, 6144);
  hipLaunchKernelGGL(transpose_cast_kernel, dim3(64, 64), dim3(32, 8), 0, stream, w_out, woutT, 2048, 2048);
  hipLaunchKernelGGL(router_kernel, dim3(4096), dim3(64), 0, stream, x, w_router, gate);
  hipLaunchKernelGGL(rope_table_kernel, dim3(128), dim3(256), 0, stream, tab);
  hipLaunchKernelGGL(gemm_bt<true>, dim3(48, 32), dim3(256), 0, stream, x_bf, wqkvT, (void*)qkv, 4096, 6144, 2048);
  hipLaunchKernelGGL(compact_kernel, dim3(128), dim3(64), 0, stream, gate, idx, counts);
  hipLaunchKernelGGL(rope_apply_kernel, dim3(8192), dim3(256), 0, stream, qkv, tab);
  hipLaunchKernelGGL(transpose_v_kernel, dim3(128, 16), dim3(256), 0, stream, qkv, vt);
  hipMemsetAsync(attn, 0, (size_t)4096 * 2048 * 2, stream);   // zero gated-out rows
  hipLaunchKernelGGL(attn_sparse_kernel, dim3(128, 16), dim3(256), 0, stream, qkv, vt, gate, idx, counts, attn);
  hipLaunchKernelGGL(gemm_bt<false>, dim3(16, 32), dim3(256), 0, stream, attn, woutT, (void*)out, 4096, 2048, 2048);
}

// Round 3
// 334.599 us; speedup vs baseline: 1.2204x; 1.0982x over previous
//
#include <hip/hip_runtime.h>
#include <hip/hip_bf16.h>
#include <stdint.h>
#include <stddef.h>

typedef __attribute__((ext_vector_type(8))) short bf16x8;       // MFMA A/B frag (8 bf16)
typedef __attribute__((ext_vector_type(8))) unsigned short u16x8;
typedef __attribute__((ext_vector_type(4))) float f32x4;        // MFMA C/D frag

#define TT 1024
#define QKV_N 6144

__device__ __forceinline__ unsigned short f2bf(float f){
  unsigned u = __builtin_bit_cast(unsigned, f);
  unsigned r = 0x7fffu + ((u >> 16) & 1u);
  return (unsigned short)((u + r) >> 16);
}
__device__ __forceinline__ float bf2f(unsigned short s){
  unsigned u = ((unsigned)s) << 16;
  return __builtin_bit_cast(float, u);
}
// async global->LDS, 16B per lane. LDS dest must be tid-linear (base + lane*16).
__device__ __forceinline__ void gload16(const unsigned short* g, unsigned short* l){
  __builtin_amdgcn_global_load_lds(
      (const __attribute__((address_space(1))) void*)g,
      (__attribute__((address_space(3))) void*)l, 16, 0, 0);
}

// ---------------- cast x (fp32 -> bf16), 4 elems/thread ----------------
__global__ void cast_x_kernel(const float* __restrict__ in, unsigned short* __restrict__ out){
  int i = blockIdx.x * 256 + threadIdx.x;
  float4 v = reinterpret_cast<const float4*>(in)[i];
  ushort4 o;
  o.x = f2bf(v.x); o.y = f2bf(v.y); o.z = f2bf(v.z); o.w = f2bf(v.w);
  reinterpret_cast<ushort4*>(out)[i] = o;
}

// ---------------- transpose + cast: in [R][C] fp32 -> out [C][R] bf16 ----------------
__global__ void transpose_cast_kernel(const float* __restrict__ in, unsigned short* __restrict__ out,
                                      int R, int C){
  __shared__ float tile[32][33];
  int c0 = blockIdx.x * 32, r0 = blockIdx.y * 32;
  for (int i = threadIdx.y; i < 32; i += 8)
    tile[i][threadIdx.x] = in[(size_t)(r0 + i) * C + c0 + threadIdx.x];
  __syncthreads();
  for (int i = threadIdx.y; i < 32; i += 8)
    out[(size_t)(c0 + i) * R + r0 + threadIdx.x] = f2bf(tile[threadIdx.x][i]);
}

// ---------------- router: logits, softmax, top-4 gate (fp32) ----------------
__global__ void router_kernel(const float* __restrict__ x, const float* __restrict__ wr,
                              float* __restrict__ gate){
  int t = blockIdx.x;
  int lane = threadIdx.x;           // 64
  int h = lane & 31, half = lane >> 5;
  const float* xr = x + (size_t)t * 2048 + half * 1024;
  const float* wp = wr + (size_t)half * 1024 * 32 + h;
  float acc = 0.f;
  #pragma unroll 4
  for (int k = 0; k < 1024; k++) acc += xr[k] * wp[k * 32];
  float other = __shfl_down(acc, 32);
  acc += other;                      // lanes 0..31 hold full logit for head h
  float logit = (lane < 32) ? acc : -3.4e38f;

  float m = logit;
  #pragma unroll
  for (int s = 16; s >= 1; s >>= 1) m = fmaxf(m, __shfl_xor(m, s));
  float e = __expf(logit - m);
  float sum = e;
  #pragma unroll
  for (int s = 16; s >= 1; s >>= 1) sum += __shfl_xor(sum, s);
  float prob = e / sum;

  // top-4 by logit; ties -> lowest index (matches lax.top_k)
  float v = logit;
  int sel = 0;
  #pragma unroll
  for (int rr = 0; rr < 4; rr++){
    float bv = v; int bi = h;
    #pragma unroll
    for (int s = 16; s >= 1; s >>= 1){
      float ov = __shfl_xor(bv, s); int oi = __shfl_xor(bi, s);
      if (ov > bv || (ov == bv && oi < bi)) { bv = ov; bi = oi; }
    }
    if (h == bi && lane < 32) { sel = 1; v = -3.4e38f; }
  }
  if (lane < 32) gate[(size_t)t * 32 + h] = sel ? prob : 0.f;
}

// ---------------- RoPE cos/sin table ----------------
__global__ void rope_table_kernel(float* __restrict__ tab){
  int idx = blockIdx.x * 256 + threadIdx.x;   // 1024*32
  int pos = idx >> 5, i = idx & 31;
  float freq = powf(10000.0f, -(float)i / 32.0f);
  float ang = (float)pos * freq;
  tab[idx * 2]     = cosf(ang);
  tab[idx * 2 + 1] = sinf(ang);
}

// ---------------- RoPE in-place on q,k sections of qkv ----------------
__global__ void rope_apply_kernel(unsigned short* __restrict__ qkv, const float* __restrict__ tab){
  int idx = blockIdx.x * 256 + threadIdx.x;   // 4096 * 512
  int t = idx >> 9;
  int cc = (idx & 511) * 8;
  int pos = t & (TT - 1);
  int i0 = (cc & 63) >> 1;
  unsigned short* p = qkv + (size_t)t * QKV_N + cc;
  u16x8 v = *(const u16x8*)p;
  const float* tp = tab + ((size_t)pos * 32 + i0) * 2;
  #pragma unroll
  for (int j = 0; j < 4; j++){
    float c = tp[j * 2], s = tp[j * 2 + 1];
    float a = bf2f(v[2 * j]), b = bf2f(v[2 * j + 1]);
    v[2 * j]     = f2bf(a * c - b * s);
    v[2 * j + 1] = f2bf(a * s + b * c);
  }
  *(u16x8*)p = v;
}

// ---------------- V transpose: qkv v-section -> vt[bh*64+d][1024] ----------------
__global__ void transpose_v_kernel(const unsigned short* __restrict__ qkv,
                                   unsigned short* __restrict__ vt){
  __shared__ unsigned short tile[64][72];
  int bh = blockIdx.x, tt = blockIdx.y;
  int b = bh >> 5, h = bh & 31;
  int tid = threadIdx.x;
  #pragma unroll
  for (int s2 = 0; s2 < 2; s2++){
    int s = s2 * 256 + tid;
    int r = s >> 3, c = (s & 7) * 8;
    u16x8 v = *(const u16x8*)(qkv + (size_t)(b * TT + tt * 64 + r) * QKV_N + 4096 + h * 64 + c);
    *(u16x8*)(&tile[r][c]) = v;
  }
  __syncthreads();
  #pragma unroll
  for (int s2 = 0; s2 < 2; s2++){
    int s = s2 * 256 + tid;
    int d = s >> 3, c = (s & 7) * 8;
    u16x8 v;
    #pragma unroll
    for (int j = 0; j < 8; j++) v[j] = tile[c + j][d];
    *(u16x8*)(vt + (size_t)(bh * 64 + d) * TT + tt * 64 + c) = v;
  }
}

// ---------------- per-(b,h) active-token compaction (order-preserving) ----------------
__global__ void compact_kernel(const float* __restrict__ gate, int* __restrict__ idx,
                               int* __restrict__ counts){
  int bh = blockIdx.x;               // 0..127
  int b = bh >> 5, h = bh & 31;
  int lane = threadIdx.x;            // 64
  int base = 0;
  for (int c = 0; c < 16; c++){
    int t = c * 64 + lane;
    bool act = gate[(size_t)(b * TT + t) * 32 + h] != 0.f;
    unsigned long long mask = __ballot(act);
    int pos = base + __popcll(mask & ((1ull << lane) - 1ull));
    if (act) idx[bh * TT + pos] = t;
    base += __popcll(mask);
  }
  if (lane == 0) counts[bh] = base;
}

// ---------------- bf16 MFMA GEMM: 3-slot LDS ring, stage-2-ahead, counted vmcnt ----------------
// C[M][N] = A[M][K] * Bt[N][K]^T.  One s_barrier per K-tile; never vmcnt(0) in steady loop.
template<bool BF16_OUT>
__global__ __launch_bounds__(256) void gemm_bt(const unsigned short* __restrict__ A,
                                               const unsigned short* __restrict__ Bt,
                                               void* __restrict__ Cv,
                                               int M, int N, int K){
  __shared__ unsigned short As[3][128 * 32];   // slot = tile % 3
  __shared__ unsigned short Bs[3][128 * 32];
  const int bn = blockIdx.x, bm = blockIdx.y;
  const int tid = threadIdx.x, lane = tid & 63, wid = tid >> 6;
  const int wr = wid >> 1, wc = wid & 1;
  const int li = lane & 15, lg = lane >> 4;

  // per-thread global staging pointers (tid-linear LDS layout: lds byte = slotidx*16)
  const unsigned short* gA0 = A  + (size_t)(bm * 128 + (tid >> 2)) * K + (tid & 3) * 8;
  const unsigned short* gA1 = gA0 + (size_t)64 * K;
  const unsigned short* gB0 = Bt + (size_t)(bn * 128 + (tid >> 2)) * K + (tid & 3) * 8;
  const unsigned short* gB1 = gB0 + (size_t)64 * K;

  f32x4 acc[4][4];
  #pragma unroll
  for (int i = 0; i < 4; i++)
    #pragma unroll
    for (int j = 0; j < 4; j++) acc[i][j] = f32x4{0.f, 0.f, 0.f, 0.f};

  const int NT = K >> 5;   // BK = 32

  // prologue: stage tiles 0 and 1
  #pragma unroll
  for (int p = 0; p < 2; p++){
    int ko = p * 32;
    gload16(gA0 + ko, &As[p][tid * 8]);
    gload16(gA1 + ko, &As[p][(256 + tid) * 8]);
    gload16(gB0 + ko, &Bs[p][tid * 8]);
    gload16(gB1 + ko, &Bs[p][(256 + tid) * 8]);
  }

  for (int t = 0; t < NT; ++t){
    // wait tile t resident: tile t+1's 4 loads may stay in flight
    if (t == NT - 1) asm volatile("s_waitcnt vmcnt(0)" ::: "memory");
    else             asm volatile("s_waitcnt vmcnt(4)" ::: "memory");
    __builtin_amdgcn_s_barrier();            // RAW: all waves see tile t; WAR: tile t-1 reads done
    __builtin_amdgcn_sched_barrier(0);

    const int sl = t % 3;
    const unsigned short* as = &As[sl][0];
    const unsigned short* bs = &Bs[sl][0];
    bf16x8 af[4], bfr[4];
    #pragma unroll
    for (int i = 0; i < 4; i++){
      af[i]  = *(const bf16x8*)(as + (wr * 64 + i * 16 + li) * 32 + lg * 8);
      bfr[i] = *(const bf16x8*)(bs + (wc * 64 + i * 16 + li) * 32 + lg * 8);
    }
    // stage tile t+2 into slot (t+2)%3 == (t-1)%3 (its readers finished before this barrier)
    if (t + 2 < NT){
      const int s2 = (t + 2) % 3;
      const int ko = (t + 2) * 32;
      gload16(gA0 + ko, &As[s2][tid * 8]);
      gload16(gA1 + ko, &As[s2][(256 + tid) * 8]);
      gload16(gB0 + ko, &Bs[s2][tid * 8]);
      gload16(gB1 + ko, &Bs[s2][(256 + tid) * 8]);
    }
    #pragma unroll
    for (int i = 0; i < 4; i++)
      #pragma unroll
      for (int j = 0; j < 4; j++)
        acc[i][j] = __builtin_amdgcn_mfma_f32_16x16x32_bf16(af[i], bfr[j], acc[i][j], 0, 0, 0);
  }

  // epilogue: C row = (lane>>4)*4 + reg, col = lane&15  [verified layout]
  #pragma unroll
  for (int i = 0; i < 4; i++){
    #pragma unroll
    for (int j = 0; j < 4; j++){
      #pragma unroll
      for (int r = 0; r < 4; r++){
        size_t row = (size_t)(bm * 128 + wr * 64 + i * 16 + lg * 4 + r);
        size_t col = (size_t)(bn * 128 + wc * 64 + j * 16 + li);
        if (BF16_OUT) ((unsigned short*)Cv)[row * N + col] = f2bf(acc[i][j][r]);
        else          ((float*)Cv)[row * N + col] = acc[i][j][r];
      }
    }
  }
}

// ---------------- sparse flash attention over gathered active q rows ----------------
__global__ __launch_bounds__(256) void attn_sparse_kernel(const unsigned short* __restrict__ qkv,
                                                          const unsigned short* __restrict__ vt,
                                                          const float* __restrict__ gate,
                                                          const int* __restrict__ idx,
                                                          const int* __restrict__ counts,
                                                          unsigned short* __restrict__ attn_out){
  __shared__ unsigned short Ks[64 * 64];      // [k][d]
  __shared__ unsigned short Vs[64 * 64];      // V^T: [d][k]
  __shared__ unsigned short Ps[4][16 * 64];   // per-wave P: [q][k]
  const int bh = blockIdx.x, qt = blockIdx.y;
  const int count = counts[bh];
  if (qt * 64 >= count) return;
  const int b = bh >> 5, h = bh & 31;
  const int tid = threadIdx.x, lane = tid & 63, w = tid >> 6;
  const int li = lane & 15, lg = lane >> 4;
  const int* myidx = idx + bh * TT + qt * 64;
  const int nvalid = min(64, count - qt * 64);
  const int qmax = myidx[nvalid - 1];         // sorted ascending

  int qi[4];
  #pragma unroll
  for (int r = 0; r < 4; r++){
    int s = w * 16 + lg * 4 + r;
    qi[r] = (s < nvalid) ? myidx[s] : -1;
  }
  int qrow = (w * 16 + li < nvalid) ? myidx[w * 16 + li] : 0;
  bf16x8 qf0, qf1;
  {
    const unsigned short* qp = qkv + (size_t)(b * TT + qrow) * QKV_N + h * 64;
    qf0 = *(const bf16x8*)(qp + lg * 8);
    qf1 = *(const bf16x8*)(qp + 32 + lg * 8);
  }
  f32x4 o[4];
  #pragma unroll
  for (int i = 0; i < 4; i++) o[i] = f32x4{0.f, 0.f, 0.f, 0.f};
  float m_run[4], l_run[4];
  #pragma unroll
  for (int r = 0; r < 4; r++){ m_run[r] = -1e30f; l_run[r] = 0.f; }

  const int nkt = (qmax >> 6) + 1;
  for (int kt = 0; kt < nkt; kt++){
    const int kb = kt * 64;
    #pragma unroll
    for (int s2 = 0; s2 < 2; s2++){
      int s = s2 * 256 + tid;
      int r = s >> 3, c = (s & 7) * 8;
      gload16(qkv + (size_t)(b * TT + kb + r) * QKV_N + 2048 + h * 64 + c, &Ks[s * 8]);
      gload16(vt + (size_t)(bh * 64 + r) * TT + kb + c, &Vs[s * 8]);
    }
    __syncthreads();

    f32x4 s4[4];
    #pragma unroll
    for (int ni = 0; ni < 4; ni++){
      bf16x8 k0 = *(const bf16x8*)(&Ks[(ni * 16 + li) * 64 + lg * 8]);
      bf16x8 k1 = *(const bf16x8*)(&Ks[(ni * 16 + li) * 64 + 32 + lg * 8]);
      f32x4 t = f32x4{0.f, 0.f, 0.f, 0.f};
      t = __builtin_amdgcn_mfma_f32_16x16x32_bf16(qf0, k0, t, 0, 0, 0);
      t = __builtin_amdgcn_mfma_f32_16x16x32_bf16(qf1, k1, t, 0, 0, 0);
      s4[ni] = t;
    }
    float mt[4];
    #pragma unroll
    for (int r = 0; r < 4; r++) mt[r] = -1e30f;
    #pragma unroll
    for (int ni = 0; ni < 4; ni++){
      int kidx = kb + ni * 16 + li;
      #pragma unroll
      for (int r = 0; r < 4; r++){
        float val = s4[ni][r] * 0.125f;
        val = (kidx <= qi[r]) ? val : -1e30f;
        s4[ni][r] = val;
        mt[r] = fmaxf(mt[r], val);
      }
    }
    #pragma unroll
    for (int r = 0; r < 4; r++){
      #pragma unroll
      for (int sh = 8; sh >= 1; sh >>= 1) mt[r] = fmaxf(mt[r], __shfl_xor(mt[r], sh));
      float mnew = fmaxf(m_run[r], mt[r]);
      float corr = __expf(m_run[r] - mnew);
      m_run[r] = mnew;
      l_run[r] *= corr;
      #pragma unroll
      for (int j = 0; j < 4; j++) o[j][r] *= corr;
    }
    float rs[4] = {0.f, 0.f, 0.f, 0.f};
    #pragma unroll
    for (int ni = 0; ni < 4; ni++)
      #pragma unroll
      for (int r = 0; r < 4; r++){
        float p = __expf(s4[ni][r] - m_run[r]);
        s4[ni][r] = p;
        rs[r] += p;
      }
    #pragma unroll
    for (int r = 0; r < 4; r++){
      #pragma unroll
      for (int sh = 8; sh >= 1; sh >>= 1) rs[r] += __shfl_xor(rs[r], sh);
      l_run[r] += rs[r];
    }
    #pragma unroll
    for (int ni = 0; ni < 4; ni++)
      #pragma unroll
      for (int r = 0; r < 4; r++)
        Ps[w][(lg * 4 + r) * 64 + ni * 16 + li] = f2bf(s4[ni][r]);
    #pragma unroll
    for (int ks = 0; ks < 2; ks++){
      bf16x8 pa = *(const bf16x8*)(&Ps[w][li * 64 + ks * 32 + lg * 8]);
      #pragma unroll
      for (int ni = 0; ni < 4; ni++){
        bf16x8 vb = *(const bf16x8*)(&Vs[(ni * 16 + li) * 64 + ks * 32 + lg * 8]);
        o[ni] = __builtin_amdgcn_mfma_f32_16x16x32_bf16(pa, vb, o[ni], 0, 0, 0);
      }
    }
    __syncthreads();
  }
  #pragma unroll
  for (int r = 0; r < 4; r++){
    if (qi[r] < 0) continue;
    float g = gate[(size_t)(b * TT + qi[r]) * 32 + h];
    float inv = g / l_run[r];
    #pragma unroll
    for (int ni = 0; ni < 4; ni++)
      attn_out[(size_t)(b * TT + qi[r]) * 2048 + h * 64 + ni * 16 + li] = f2bf(o[ni][r] * inv);
  }
}

extern "C" void kernel_launch(void* const* d_in, const int* in_sizes, int n_in,
                              void* d_out, int out_size, void* d_ws, size_t ws_size,
                              hipStream_t stream){
  const float* x        = (const float*)d_in[0];
  const float* w_router = (const float*)d_in[1];
  const float* w_qkv    = (const float*)d_in[2];
  const float* w_out    = (const float*)d_in[3];
  float* out = (float*)d_out;
  char* ws = (char*)d_ws;

  unsigned short* qkv   = (unsigned short*)(ws);                        // 50331648 B
  unsigned short* x_bf  = (unsigned short*)(ws + 50331648);             // 16777216 B
  unsigned short* wqkvT = (unsigned short*)(ws + 67108864);             // 25165824 B
  unsigned short* woutT = (unsigned short*)(ws + 92274688);             // 8388608 B
  float* gate           = (float*)(ws + 100663296);                     // 524288 B
  float* tab            = (float*)(ws + 101187584);                     // 262144 B
  unsigned short* attn  = x_bf;                      // reuse after qkv GEMM
  unsigned short* vt    = wqkvT;                     // reuse after qkv GEMM (16.8 MB)
  int* idx              = (int*)(ws + 83886080);     // in wqkvT region, after vt
  int* counts           = (int*)(ws + 84410368);

  hipLaunchKernelGGL(cast_x_kernel, dim3(8192), dim3(256), 0, stream, x, x_bf);
  hipLaunchKernelGGL(transpose_cast_kernel, dim3(192, 64), dim3(32, 8), 0, stream, w_qkv, wqkvT, 2048, 6144);
  hipLaunchKernelGGL(transpose_cast_kernel, dim3(64, 64), dim3(32, 8), 0, stream, w_out, woutT, 2048, 2048);
  hipLaunchKernelGGL(router_kernel, dim3(4096), dim3(64), 0, stream, x, w_router, gate);
  hipLaunchKernelGGL(rope_table_kernel, dim3(128), dim3(256), 0, stream, tab);
  hipLaunchKernelGGL(gemm_bt<true>, dim3(48, 32), dim3(256), 0, stream, x_bf, wqkvT, (void*)qkv, 4096, 6144, 2048);
  hipLaunchKernelGGL(compact_kernel, dim3(128), dim3(64), 0, stream, gate, idx, counts);
  hipLaunchKernelGGL(rope_apply_kernel, dim3(8192), dim3(256), 0, stream, qkv, tab);
  hipLaunchKernelGGL(transpose_v_kernel, dim3(128, 16), dim3(256), 0, stream, qkv, vt);
  hipMemsetAsync(attn, 0, (size_t)4096 * 2048 * 2, stream);   // zero gated-out rows
  hipLaunchKernelGGL(attn_sparse_kernel, dim3(128, 16), dim3(256), 0, stream, qkv, vt, gate, idx, counts, attn);
  hipLaunchKernelGGL(gemm_bt<false>, dim3(16, 32), dim3(256), 0, stream, attn, woutT, (void*)out, 4096, 2048, 2048);
}

// Round 4
// 274.904 us; speedup vs baseline: 1.4854x; 1.2171x over previous
//
#include <hip/hip_runtime.h>
#include <hip/hip_bf16.h>
#include <stdint.h>
#include <stddef.h>

typedef __attribute__((ext_vector_type(8))) short bf16x8;       // MFMA A/B frag (8 bf16)
typedef __attribute__((ext_vector_type(8))) unsigned short u16x8;
typedef __attribute__((ext_vector_type(4))) float f32x4;        // MFMA C/D frag

#define TT 1024

__device__ __forceinline__ unsigned short f2bf(float f){
  unsigned u = __builtin_bit_cast(unsigned, f);
  unsigned r = 0x7fffu + ((u >> 16) & 1u);
  return (unsigned short)((u + r) >> 16);
}
__device__ __forceinline__ float bf2f(unsigned short s){
  unsigned u = ((unsigned)s) << 16;
  return __builtin_bit_cast(float, u);
}
// async global->LDS, 16B per lane. LDS dest must be tid-linear (base + lane*16).
__device__ __forceinline__ void gload16(const unsigned short* g, unsigned short* l){
  __builtin_amdgcn_global_load_lds(
      (const __attribute__((address_space(1))) void*)g,
      (__attribute__((address_space(3))) void*)l, 16, 0, 0);
}

// ---------------- transpose + cast: in [R][C] fp32 -> out [C][R] bf16 ----------------
__global__ void transpose_cast_kernel(const float* __restrict__ in, unsigned short* __restrict__ out,
                                      int R, int C){
  __shared__ float tile[32][33];
  int c0 = blockIdx.x * 32, r0 = blockIdx.y * 32;
  for (int i = threadIdx.y; i < 32; i += 8)
    tile[i][threadIdx.x] = in[(size_t)(r0 + i) * C + c0 + threadIdx.x];
  __syncthreads();
  for (int i = threadIdx.y; i < 32; i += 8)
    out[(size_t)(c0 + i) * R + r0 + threadIdx.x] = f2bf(tile[threadIdx.x][i]);
}

// ---------------- RoPE cos/sin table ----------------
__global__ void rope_table_kernel(float* __restrict__ tab){
  int idx = blockIdx.x * 256 + threadIdx.x;   // 1024*32
  int pos = idx >> 5, i = idx & 31;
  float freq = powf(10000.0f, -(float)i / 32.0f);
  float ang = (float)pos * freq;
  tab[idx * 2]     = cosf(ang);
  tab[idx * 2 + 1] = sinf(ang);
}

// ---------------- fused: x cast->bf16 + router softmax/top4 gate (fp32) ----------------
// 8 tokens per block; w_router k-blocked into registers (L2 traffic /16 vs per-token).
__global__ __launch_bounds__(256) void prep_kernel(const float* __restrict__ x,
                                                   const float* __restrict__ wr,
                                                   unsigned short* __restrict__ x_bf,
                                                   float* __restrict__ gate){
  __shared__ float xc[8 * 256];          // current k-chunk, 8 tokens
  __shared__ float red[8 * 8 * 32];      // [p][tok][h]
  const int tid = threadIdx.x;
  const int tok0 = blockIdx.x * 8;
  const int p = tid >> 5, h = tid & 31;
  float acc[8] = {0.f,0.f,0.f,0.f,0.f,0.f,0.f,0.f};

  for (int kb = 0; kb < 8; kb++){
    __syncthreads();                     // xc WAR from previous iteration
    {
      int tok = tid >> 5, e = (tid & 31) * 8;
      const float* xp = x + (size_t)(tok0 + tok) * 2048 + kb * 256 + e;
      float4 v0 = *(const float4*)xp, v1 = *(const float4*)(xp + 4);
      float vals[8] = {v0.x, v0.y, v0.z, v0.w, v1.x, v1.y, v1.z, v1.w};
      u16x8 ob;
      #pragma unroll
      for (int jj = 0; jj < 8; jj++) ob[jj] = f2bf(vals[jj]);
      *(u16x8*)(x_bf + (size_t)(tok0 + tok) * 2048 + kb * 256 + e) = ob;
      #pragma unroll
      for (int jj = 0; jj < 8; jj++) xc[tok * 256 + e + jj] = vals[jj];
    }
    __syncthreads();
    const float* wp = wr + (size_t)(kb * 256 + p * 32) * 32 + h;
    #pragma unroll 4
    for (int j = 0; j < 32; j++){
      float wv = wp[j * 32];
      #pragma unroll
      for (int tok = 0; tok < 8; tok++)
        acc[tok] += xc[tok * 256 + p * 32 + j] * wv;
    }
  }
  #pragma unroll
  for (int tok = 0; tok < 8; tok++) red[(p * 8 + tok) * 32 + h] = acc[tok];
  __syncthreads();

  // 4 waves x 2 tokens; all shuffles stay within 32-lane groups
  {
    int lane = tid & 63;
    int tok = (tid >> 6) * 2 + (lane >> 5);
    int hh = lane & 31;
    float logit = 0.f;
    #pragma unroll
    for (int pp = 0; pp < 8; pp++) logit += red[(pp * 8 + tok) * 32 + hh];
    float m = logit;
    #pragma unroll
    for (int s = 16; s >= 1; s >>= 1) m = fmaxf(m, __shfl_xor(m, s));
    float e = __expf(logit - m);
    float sum = e;
    #pragma unroll
    for (int s = 16; s >= 1; s >>= 1) sum += __shfl_xor(sum, s);
    float prob = e / sum;
    // top-4 by logit; ties -> lowest index (matches lax.top_k)
    float v = logit; int sel = 0;
    #pragma unroll
    for (int rr2 = 0; rr2 < 4; rr2++){
      float bv = v; int bi = hh;
      #pragma unroll
      for (int s = 16; s >= 1; s >>= 1){
        float ov = __shfl_xor(bv, s); int oi = __shfl_xor(bi, s);
        if (ov > bv || (ov == bv && oi < bi)) { bv = ov; bi = oi; }
      }
      if (hh == bi) { sel = 1; v = -3.4e38f; }
    }
    gate[(size_t)(tok0 + tok) * 32 + hh] = sel ? prob : 0.f;
  }
}

// ---------------- per-(b,h) active-token compaction (order-preserving) ----------------
__global__ void compact_kernel(const float* __restrict__ gate, int* __restrict__ idx,
                               int* __restrict__ counts){
  int bh = blockIdx.x;               // 0..127
  int b = bh >> 5, h = bh & 31;
  int lane = threadIdx.x;            // 64
  int base = 0;
  for (int c = 0; c < 16; c++){
    int t = c * 64 + lane;
    bool act = gate[(size_t)(b * TT + t) * 32 + h] != 0.f;
    unsigned long long mask = __ballot(act);
    int pos = base + __popcll(mask & ((1ull << lane) - 1ull));
    if (act) idx[bh * TT + pos] = t;
    base += __popcll(mask);
  }
  if (lane == 0) counts[bh] = base;
}

// ---------------- QKV GEMM: 3-slot ring + counted vmcnt; fused RoPE + V-transpose epilogue ----
// A[4096][2048] bf16, Bt[6144][2048] bf16.  bn<32 -> roped q/k into qk[4096][4096];
// bn>=32 -> V written transposed into vt[(b*32+h)*64+d][1024].
__global__ __launch_bounds__(256) void gemm_qkv(const unsigned short* __restrict__ A,
                                                const unsigned short* __restrict__ Bt,
                                                unsigned short* __restrict__ qk,
                                                unsigned short* __restrict__ vt,
                                                const float* __restrict__ tab){
  __shared__ unsigned short As[3][128 * 32];
  __shared__ unsigned short Bs[3][128 * 32];
  const int K = 2048;
  const int bn = blockIdx.x, bm = blockIdx.y;
  const int tid = threadIdx.x, lane = tid & 63, wid = tid >> 6;
  const int wr = wid >> 1, wc = wid & 1;
  const int li = lane & 15, lg = lane >> 4;

  const unsigned short* gA0 = A  + (size_t)(bm * 128 + (tid >> 2)) * K + (tid & 3) * 8;
  const unsigned short* gA1 = gA0 + (size_t)64 * K;
  const unsigned short* gB0 = Bt + (size_t)(bn * 128 + (tid >> 2)) * K + (tid & 3) * 8;
  const unsigned short* gB1 = gB0 + (size_t)64 * K;

  f32x4 acc[4][4];
  #pragma unroll
  for (int i = 0; i < 4; i++)
    #pragma unroll
    for (int j = 0; j < 4; j++) acc[i][j] = f32x4{0.f, 0.f, 0.f, 0.f};

  const int NT = K >> 5;
  #pragma unroll
  for (int pp = 0; pp < 2; pp++){
    int ko = pp * 32;
    gload16(gA0 + ko, &As[pp][tid * 8]);
    gload16(gA1 + ko, &As[pp][(256 + tid) * 8]);
    gload16(gB0 + ko, &Bs[pp][tid * 8]);
    gload16(gB1 + ko, &Bs[pp][(256 + tid) * 8]);
  }
  for (int t = 0; t < NT; ++t){
    if (t == NT - 1) asm volatile("s_waitcnt vmcnt(0)" ::: "memory");
    else             asm volatile("s_waitcnt vmcnt(4)" ::: "memory");
    __builtin_amdgcn_s_barrier();
    __builtin_amdgcn_sched_barrier(0);
    const int sl = t % 3;
    const unsigned short* as = &As[sl][0];
    const unsigned short* bs = &Bs[sl][0];
    bf16x8 af[4], bfr[4];
    #pragma unroll
    for (int i = 0; i < 4; i++){
      af[i]  = *(const bf16x8*)(as + (wr * 64 + i * 16 + li) * 32 + lg * 8);
      bfr[i] = *(const bf16x8*)(bs + (wc * 64 + i * 16 + li) * 32 + lg * 8);
    }
    if (t + 2 < NT){
      const int s2 = (t + 2) % 3;
      const int ko = (t + 2) * 32;
      gload16(gA0 + ko, &As[s2][tid * 8]);
      gload16(gA1 + ko, &As[s2][(256 + tid) * 8]);
      gload16(gB0 + ko, &Bs[s2][tid * 8]);
      gload16(gB1 + ko, &Bs[s2][(256 + tid) * 8]);
    }
    #pragma unroll
    for (int i = 0; i < 4; i++)
      #pragma unroll
      for (int j = 0; j < 4; j++)
        acc[i][j] = __builtin_amdgcn_mfma_f32_16x16x32_bf16(af[i], bfr[j], acc[i][j], 0, 0, 0);
  }

  // epilogue (C row = lg*4+reg, col = li within each 16x16 frag)
  if (bn < 32){
    // q (cols 0..2047) / k (2048..4095): apply RoPE pre-rounding, write to qk[row][col]
    #pragma unroll
    for (int i = 0; i < 4; i++){
      #pragma unroll
      for (int j = 0; j < 4; j++){
        int col = bn * 128 + wc * 64 + j * 16 + li;
        int ii = (col & 63) >> 1;
        #pragma unroll
        for (int r = 0; r < 4; r++){
          int row = bm * 128 + wr * 64 + i * 16 + lg * 4 + r;
          int pos = row & (TT - 1);
          const float* tp = tab + ((size_t)pos * 32 + ii) * 2;
          float c = tp[0], s = tp[1];
          float val = acc[i][j][r];
          float pv = __shfl_xor(val, 1);
          float res = (li & 1) ? (pv * s + val * c) : (val * c - pv * s);
          qk[(size_t)row * 4096 + col] = f2bf(res);
        }
      }
    }
  } else {
    // v (cols 4096..6143): write transposed vt[(b*32+h)*64+d][t], 4 t's packed per store
    #pragma unroll
    for (int i = 0; i < 4; i++){
      #pragma unroll
      for (int j = 0; j < 4; j++){
        int vcol = bn * 128 + wc * 64 + j * 16 + li - 4096;   // 0..2047
        int hh = vcol >> 6, d = vcol & 63;
        int row0 = bm * 128 + wr * 64 + i * 16 + lg * 4;
        int b = row0 >> 10, t0 = row0 & (TT - 1);
        ushort4 pk;
        pk.x = f2bf(acc[i][j][0]); pk.y = f2bf(acc[i][j][1]);
        pk.z = f2bf(acc[i][j][2]); pk.w = f2bf(acc[i][j][3]);
        *(ushort4*)(vt + ((size_t)((b * 32 + hh) * 64 + d)) * TT + t0) = pk;
      }
    }
  }
}

// ---------------- generic GEMM for the output projection (fp32 out) ----------------
__global__ __launch_bounds__(256) void gemm_out(const unsigned short* __restrict__ A,
                                                const unsigned short* __restrict__ Bt,
                                                float* __restrict__ C,
                                                int M, int N, int K){
  __shared__ unsigned short As[3][128 * 32];
  __shared__ unsigned short Bs[3][128 * 32];
  const int bn = blockIdx.x, bm = blockIdx.y;
  const int tid = threadIdx.x, lane = tid & 63, wid = tid >> 6;
  const int wr = wid >> 1, wc = wid & 1;
  const int li = lane & 15, lg = lane >> 4;
  const unsigned short* gA0 = A  + (size_t)(bm * 128 + (tid >> 2)) * K + (tid & 3) * 8;
  const unsigned short* gA1 = gA0 + (size_t)64 * K;
  const unsigned short* gB0 = Bt + (size_t)(bn * 128 + (tid >> 2)) * K + (tid & 3) * 8;
  const unsigned short* gB1 = gB0 + (size_t)64 * K;
  f32x4 acc[4][4];
  #pragma unroll
  for (int i = 0; i < 4; i++)
    #pragma unroll
    for (int j = 0; j < 4; j++) acc[i][j] = f32x4{0.f, 0.f, 0.f, 0.f};
  const int NT = K >> 5;
  #pragma unroll
  for (int pp = 0; pp < 2; pp++){
    int ko = pp * 32;
    gload16(gA0 + ko, &As[pp][tid * 8]);
    gload16(gA1 + ko, &As[pp][(256 + tid) * 8]);
    gload16(gB0 + ko, &Bs[pp][tid * 8]);
    gload16(gB1 + ko, &Bs[pp][(256 + tid) * 8]);
  }
  for (int t = 0; t < NT; ++t){
    if (t == NT - 1) asm volatile("s_waitcnt vmcnt(0)" ::: "memory");
    else             asm volatile("s_waitcnt vmcnt(4)" ::: "memory");
    __builtin_amdgcn_s_barrier();
    __builtin_amdgcn_sched_barrier(0);
    const int sl = t % 3;
    const unsigned short* as = &As[sl][0];
    const unsigned short* bs = &Bs[sl][0];
    bf16x8 af[4], bfr[4];
    #pragma unroll
    for (int i = 0; i < 4; i++){
      af[i]  = *(const bf16x8*)(as + (wr * 64 + i * 16 + li) * 32 + lg * 8);
      bfr[i] = *(const bf16x8*)(bs + (wc * 64 + i * 16 + li) * 32 + lg * 8);
    }
    if (t + 2 < NT){
      const int s2 = (t + 2) % 3;
      const int ko = (t + 2) * 32;
      gload16(gA0 + ko, &As[s2][tid * 8]);
      gload16(gA1 + ko, &As[s2][(256 + tid) * 8]);
      gload16(gB0 + ko, &Bs[s2][tid * 8]);
      gload16(gB1 + ko, &Bs[s2][(256 + tid) * 8]);
    }
    #pragma unroll
    for (int i = 0; i < 4; i++)
      #pragma unroll
      for (int j = 0; j < 4; j++)
        acc[i][j] = __builtin_amdgcn_mfma_f32_16x16x32_bf16(af[i], bfr[j], acc[i][j], 0, 0, 0);
  }
  #pragma unroll
  for (int i = 0; i < 4; i++)
    #pragma unroll
    for (int j = 0; j < 4; j++)
      #pragma unroll
      for (int r = 0; r < 4; r++){
        size_t row = (size_t)(bm * 128 + wr * 64 + i * 16 + lg * 4 + r);
        size_t col = (size_t)(bn * 128 + wc * 64 + j * 16 + li);
        C[row * N + col] = acc[i][j][r];
      }
}

// ---------------- sparse flash attention over gathered active q rows ----------------
__global__ __launch_bounds__(256) void attn_sparse_kernel(const unsigned short* __restrict__ qk,
                                                          const unsigned short* __restrict__ vt,
                                                          const float* __restrict__ gate,
                                                          const int* __restrict__ idx,
                                                          const int* __restrict__ counts,
                                                          unsigned short* __restrict__ attn_out){
  __shared__ unsigned short Ks[64 * 64];      // [k][d]
  __shared__ unsigned short Vs[64 * 64];      // V^T: [d][k]
  __shared__ unsigned short Ps[4][16 * 64];   // per-wave P: [q][k]
  const int bh = blockIdx.x, qt = blockIdx.y;
  const int count = counts[bh];
  if (qt * 64 >= count) return;
  const int b = bh >> 5, h = bh & 31;
  const int tid = threadIdx.x, lane = tid & 63, w = tid >> 6;
  const int li = lane & 15, lg = lane >> 4;
  const int* myidx = idx + bh * TT + qt * 64;
  const int nvalid = min(64, count - qt * 64);
  const int qmax = myidx[nvalid - 1];

  int qi[4];
  #pragma unroll
  for (int r = 0; r < 4; r++){
    int s = w * 16 + lg * 4 + r;
    qi[r] = (s < nvalid) ? myidx[s] : -1;
  }
  int qrow = (w * 16 + li < nvalid) ? myidx[w * 16 + li] : 0;
  bf16x8 qf0, qf1;
  {
    const unsigned short* qp = qk + (size_t)(b * TT + qrow) * 4096 + h * 64;
    qf0 = *(const bf16x8*)(qp + lg * 8);
    qf1 = *(const bf16x8*)(qp + 32 + lg * 8);
  }
  f32x4 o[4];
  #pragma unroll
  for (int i = 0; i < 4; i++) o[i] = f32x4{0.f, 0.f, 0.f, 0.f};
  float m_run[4], l_run[4];
  #pragma unroll
  for (int r = 0; r < 4; r++){ m_run[r] = -1e30f; l_run[r] = 0.f; }

  const int nkt = (qmax >> 6) + 1;
  for (int kt = 0; kt < nkt; kt++){
    const int kb = kt * 64;
    #pragma unroll
    for (int s2 = 0; s2 < 2; s2++){
      int s = s2 * 256 + tid;
      int r = s >> 3, c = (s & 7) * 8;
      gload16(qk + (size_t)(b * TT + kb + r) * 4096 + 2048 + h * 64 + c, &Ks[s * 8]);
      gload16(vt + (size_t)(bh * 64 + r) * TT + kb + c, &Vs[s * 8]);
    }
    __syncthreads();

    f32x4 s4[4];
    #pragma unroll
    for (int ni = 0; ni < 4; ni++){
      bf16x8 k0 = *(const bf16x8*)(&Ks[(ni * 16 + li) * 64 + lg * 8]);
      bf16x8 k1 = *(const bf16x8*)(&Ks[(ni * 16 + li) * 64 + 32 + lg * 8]);
      f32x4 t = f32x4{0.f, 0.f, 0.f, 0.f};
      t = __builtin_amdgcn_mfma_f32_16x16x32_bf16(qf0, k0, t, 0, 0, 0);
      t = __builtin_amdgcn_mfma_f32_16x16x32_bf16(qf1, k1, t, 0, 0, 0);
      s4[ni] = t;
    }
    float mt[4];
    #pragma unroll
    for (int r = 0; r < 4; r++) mt[r] = -1e30f;
    #pragma unroll
    for (int ni = 0; ni < 4; ni++){
      int kidx = kb + ni * 16 + li;
      #pragma unroll
      for (int r = 0; r < 4; r++){
        float val = s4[ni][r] * 0.125f;
        val = (kidx <= qi[r]) ? val : -1e30f;
        s4[ni][r] = val;
        mt[r] = fmaxf(mt[r], val);
      }
    }
    #pragma unroll
    for (int r = 0; r < 4; r++){
      #pragma unroll
      for (int sh = 8; sh >= 1; sh >>= 1) mt[r] = fmaxf(mt[r], __shfl_xor(mt[r], sh));
      float mnew = fmaxf(m_run[r], mt[r]);
      float corr = __expf(m_run[r] - mnew);
      m_run[r] = mnew;
      l_run[r] *= corr;
      #pragma unroll
      for (int j = 0; j < 4; j++) o[j][r] *= corr;
    }
    float rs[4] = {0.f, 0.f, 0.f, 0.f};
    #pragma unroll
    for (int ni = 0; ni < 4; ni++)
      #pragma unroll
      for (int r = 0; r < 4; r++){
        float p = __expf(s4[ni][r] - m_run[r]);
        s4[ni][r] = p;
        rs[r] += p;
      }
    #pragma unroll
    for (int r = 0; r < 4; r++){
      #pragma unroll
      for (int sh = 8; sh >= 1; sh >>= 1) rs[r] += __shfl_xor(rs[r], sh);
      l_run[r] += rs[r];
    }
    #pragma unroll
    for (int ni = 0; ni < 4; ni++)
      #pragma unroll
      for (int r = 0; r < 4; r++)
        Ps[w][(lg * 4 + r) * 64 + ni * 16 + li] = f2bf(s4[ni][r]);
    #pragma unroll
    for (int ks = 0; ks < 2; ks++){
      bf16x8 pa = *(const bf16x8*)(&Ps[w][li * 64 + ks * 32 + lg * 8]);
      #pragma unroll
      for (int ni = 0; ni < 4; ni++){
        bf16x8 vb = *(const bf16x8*)(&Vs[(ni * 16 + li) * 64 + ks * 32 + lg * 8]);
        o[ni] = __builtin_amdgcn_mfma_f32_16x16x32_bf16(pa, vb, o[ni], 0, 0, 0);
      }
    }
    __syncthreads();
  }
  #pragma unroll
  for (int r = 0; r < 4; r++){
    if (qi[r] < 0) continue;
    float g = gate[(size_t)(b * TT + qi[r]) * 32 + h];
    float inv = g / l_run[r];
    #pragma unroll
    for (int ni = 0; ni < 4; ni++)
      attn_out[(size_t)(b * TT + qi[r]) * 2048 + h * 64 + ni * 16 + li] = f2bf(o[ni][r] * inv);
  }
}

extern "C" void kernel_launch(void* const* d_in, const int* in_sizes, int n_in,
                              void* d_out, int out_size, void* d_ws, size_t ws_size,
                              hipStream_t stream){
  const float* x        = (const float*)d_in[0];
  const float* w_router = (const float*)d_in[1];
  const float* w_qkv    = (const float*)d_in[2];
  const float* w_out    = (const float*)d_in[3];
  float* out = (float*)d_out;
  char* ws = (char*)d_ws;

  unsigned short* qk    = (unsigned short*)(ws);                        // 33554432 B [4096][4096]
  unsigned short* vt    = (unsigned short*)(ws + 33554432);             // 16777216 B
  unsigned short* x_bf  = (unsigned short*)(ws + 50331648);             // 16777216 B
  unsigned short* wqkvT = (unsigned short*)(ws + 67108864);             // 25165824 B
  unsigned short* woutT = (unsigned short*)(ws + 92274688);             // 8388608 B
  float* gate           = (float*)(ws + 100663296);                     // 524288 B
  float* tab            = (float*)(ws + 101187584);                     // 262144 B  (peak 101449728)
  unsigned short* attn  = x_bf;                      // reuse after qkv GEMM
  int* idx              = (int*)(ws + 67108864);     // reuse wqkvT region after qkv GEMM
  int* counts           = (int*)(ws + 67633152);

  hipLaunchKernelGGL(transpose_cast_kernel, dim3(192, 64), dim3(32, 8), 0, stream, w_qkv, wqkvT, 2048, 6144);
  hipLaunchKernelGGL(transpose_cast_kernel, dim3(64, 64), dim3(32, 8), 0, stream, w_out, woutT, 2048, 2048);
  hipLaunchKernelGGL(rope_table_kernel, dim3(128), dim3(256), 0, stream, tab);
  hipLaunchKernelGGL(prep_kernel, dim3(512), dim3(256), 0, stream, x, w_router, x_bf, gate);
  hipLaunchKernelGGL(gemm_qkv, dim3(48, 32), dim3(256), 0, stream, x_bf, wqkvT, qk, vt, tab);
  hipLaunchKernelGGL(compact_kernel, dim3(128), dim3(64), 0, stream, gate, idx, counts);
  hipMemsetAsync(attn, 0, (size_t)4096 * 2048 * 2, stream);   // zero gated-out rows
  hipLaunchKernelGGL(attn_sparse_kernel, dim3(128, 16), dim3(256), 0, stream, qk, vt, gate, idx, counts, attn);
  hipLaunchKernelGGL(gemm_out, dim3(16, 32), dim3(256), 0, stream, attn, woutT, out, 4096, 2048, 2048);
}

// Round 6
// 262.838 us; speedup vs baseline: 1.5536x; 1.0459x over previous
//
#include <hip/hip_runtime.h>
#include <hip/hip_bf16.h>
#include <stdint.h>
#include <stddef.h>

typedef __attribute__((ext_vector_type(8))) short bf16x8;       // MFMA A/B frag (8 bf16)
typedef __attribute__((ext_vector_type(8))) unsigned short u16x8;
typedef __attribute__((ext_vector_type(4))) float f32x4;        // MFMA C/D frag

#define TT 1024

__device__ __forceinline__ unsigned short f2bf(float f){
  unsigned u = __builtin_bit_cast(unsigned, f);
  unsigned r = 0x7fffu + ((u >> 16) & 1u);
  return (unsigned short)((u + r) >> 16);
}
__device__ __forceinline__ float bf2f(unsigned short s){
  unsigned u = ((unsigned)s) << 16;
  return __builtin_bit_cast(float, u);
}
// async global->LDS, 16B per lane. LDS dest must be tid-linear (base + lane*16).
__device__ __forceinline__ void gload16(const unsigned short* g, unsigned short* l){
  __builtin_amdgcn_global_load_lds(
      (const __attribute__((address_space(1))) void*)g,
      (__attribute__((address_space(3))) void*)l, 16, 0, 0);
}

// ---------------- transpose + cast: in [R][C] fp32 -> out [C][R] bf16 ----------------
__global__ void transpose_cast_kernel(const float* __restrict__ in, unsigned short* __restrict__ out,
                                      int R, int C){
  __shared__ float tile[32][33];
  int c0 = blockIdx.x * 32, r0 = blockIdx.y * 32;
  for (int i = threadIdx.y; i < 32; i += 8)
    tile[i][threadIdx.x] = in[(size_t)(r0 + i) * C + c0 + threadIdx.x];
  __syncthreads();
  for (int i = threadIdx.y; i < 32; i += 8)
    out[(size_t)(c0 + i) * R + r0 + threadIdx.x] = f2bf(tile[threadIdx.x][i]);
}

// ---------------- RoPE cos/sin table ----------------
__global__ void rope_table_kernel(float* __restrict__ tab){
  int idx = blockIdx.x * 256 + threadIdx.x;   // 1024*32
  int pos = idx >> 5, i = idx & 31;
  float freq = powf(10000.0f, -(float)i / 32.0f);
  float ang = (float)pos * freq;
  tab[idx * 2]     = cosf(ang);
  tab[idx * 2 + 1] = sinf(ang);
}

// ---------------- fused: x cast->bf16 + router softmax/top4 gate (fp32) ----------------
__global__ __launch_bounds__(256) void prep_kernel(const float* __restrict__ x,
                                                   const float* __restrict__ wr,
                                                   unsigned short* __restrict__ x_bf,
                                                   float* __restrict__ gate){
  __shared__ float xc[8 * 256];
  __shared__ float red[8 * 8 * 32];
  const int tid = threadIdx.x;
  const int tok0 = blockIdx.x * 8;
  const int p = tid >> 5, h = tid & 31;
  float acc[8] = {0.f,0.f,0.f,0.f,0.f,0.f,0.f,0.f};

  for (int kb = 0; kb < 8; kb++){
    __syncthreads();
    {
      int tok = tid >> 5, e = (tid & 31) * 8;
      const float* xp = x + (size_t)(tok0 + tok) * 2048 + kb * 256 + e;
      float4 v0 = *(const float4*)xp, v1 = *(const float4*)(xp + 4);
      float vals[8] = {v0.x, v0.y, v0.z, v0.w, v1.x, v1.y, v1.z, v1.w};
      u16x8 ob;
      #pragma unroll
      for (int jj = 0; jj < 8; jj++) ob[jj] = f2bf(vals[jj]);
      *(u16x8*)(x_bf + (size_t)(tok0 + tok) * 2048 + kb * 256 + e) = ob;
      #pragma unroll
      for (int jj = 0; jj < 8; jj++) xc[tok * 256 + e + jj] = vals[jj];
    }
    __syncthreads();
    const float* wp = wr + (size_t)(kb * 256 + p * 32) * 32 + h;
    #pragma unroll 4
    for (int j = 0; j < 32; j++){
      float wv = wp[j * 32];
      #pragma unroll
      for (int tok = 0; tok < 8; tok++)
        acc[tok] += xc[tok * 256 + p * 32 + j] * wv;
    }
  }
  #pragma unroll
  for (int tok = 0; tok < 8; tok++) red[(p * 8 + tok) * 32 + h] = acc[tok];
  __syncthreads();
  {
    int lane = tid & 63;
    int tok = (tid >> 6) * 2 + (lane >> 5);
    int hh = lane & 31;
    float logit = 0.f;
    #pragma unroll
    for (int pp = 0; pp < 8; pp++) logit += red[(pp * 8 + tok) * 32 + hh];
    float m = logit;
    #pragma unroll
    for (int s = 16; s >= 1; s >>= 1) m = fmaxf(m, __shfl_xor(m, s));
    float e = __expf(logit - m);
    float sum = e;
    #pragma unroll
    for (int s = 16; s >= 1; s >>= 1) sum += __shfl_xor(sum, s);
    float prob = e / sum;
    float v = logit; int sel = 0;
    #pragma unroll
    for (int rr2 = 0; rr2 < 4; rr2++){
      float bv = v; int bi = hh;
      #pragma unroll
      for (int s = 16; s >= 1; s >>= 1){
        float ov = __shfl_xor(bv, s); int oi = __shfl_xor(bi, s);
        if (ov > bv || (ov == bv && oi < bi)) { bv = ov; bi = oi; }
      }
      if (hh == bi) { sel = 1; v = -3.4e38f; }
    }
    gate[(size_t)(tok0 + tok) * 32 + hh] = sel ? prob : 0.f;
  }
}

// ---------------- per-(b,h) active-token compaction (order-preserving) ----------------
__global__ void compact_kernel(const float* __restrict__ gate, int* __restrict__ idx,
                               int* __restrict__ counts){
  int bh = blockIdx.x;
  int b = bh >> 5, h = bh & 31;
  int lane = threadIdx.x;
  int base = 0;
  for (int c = 0; c < 16; c++){
    int t = c * 64 + lane;
    bool act = gate[(size_t)(b * TT + t) * 32 + h] != 0.f;
    unsigned long long mask = __ballot(act);
    int pos = base + __popcll(mask & ((1ull << lane) - 1ull));
    if (act) idx[bh * TT + pos] = t;
    base += __popcll(mask);
  }
  if (lane == 0) counts[bh] = base;
}

// ======== 8-phase-style GEMM: BM=256, BN=128, BK=64, 512 thr (8 waves 4Mx2N) ========
// 3-slot LDS ring (144KB dynamic), counted vmcnt(6), T2 xor-swizzle, T5 setprio.
// EPI=0: C fp32.  EPI=1: QKV fused epilogue (RoPE q/k -> qk, transposed V -> vt).
#define MFMA_B16(a, b, c) __builtin_amdgcn_mfma_f32_16x16x32_bf16((a), (b), (c), 0, 0, 0)

template<int EPI>
__global__ __launch_bounds__(512, 2) void gemm8(const unsigned short* __restrict__ A,
                                                const unsigned short* __restrict__ Bt,
                                                float* __restrict__ Cf,
                                                unsigned short* __restrict__ qk,
                                                unsigned short* __restrict__ vt,
                                                const float* __restrict__ tab,
                                                int N, int K, int nbn){
  extern __shared__ unsigned short smem[];
  unsigned short* SA = smem;             // 3 slots x 16384 ushorts (256x64 bf16)
  unsigned short* SB = smem + 49152;     // 3 slots x  8192 ushorts (128x64 bf16)

  // T1: bijective XCD swizzle (grid % 8 == 0), bm-major chunks
  const int nblk = gridDim.x;
  int raw = blockIdx.x;
  int tile = (raw & 7) * (nblk >> 3) + (raw >> 3);
  const int bm = tile / nbn, bn = tile % nbn;

  const int tid = threadIdx.x, lane = tid & 63, wid = tid >> 6;
  const int wrow = wid >> 1, wcol = wid & 1;
  const int li = lane & 15, lg = lane >> 4;
  const int swz = (li & 7) << 4;

  // swizzled ds_read offsets (ushort idx); frag i adds i*1024
  const int aoff0 = (((wrow * 64 + li) * 128) + ((lg * 16) ^ swz)) >> 1;        // k-half 0
  const int aoff1 = (((wrow * 64 + li) * 128) + ((64 + lg * 16) ^ swz)) >> 1;   // k-half 1
  const int boff0 = (((wcol * 64 + li) * 128) + ((lg * 16) ^ swz)) >> 1;
  const int boff1 = (((wcol * 64 + li) * 128) + ((64 + lg * 16) ^ swz)) >> 1;

  // staging precompute: linear LDS dest, inverse-swizzled GLOBAL source (rule 21)
  int L0 = tid * 16,            r0_ = L0 >> 7, c0_ = (L0 & 127) ^ ((r0_ & 7) << 4);
  int L1 = 8192 + tid * 16,     r1_ = L1 >> 7, c1_ = (L1 & 127) ^ ((r1_ & 7) << 4);
  int L2 = 16384 + tid * 16,    r2_ = L2 >> 7, c2_ = (L2 & 127) ^ ((r2_ & 7) << 4);
  int L3 = 24576 + tid * 16,    r3_ = L3 >> 7, c3_ = (L3 & 127) ^ ((r3_ & 7) << 4);
  const unsigned short* gA0p = A + (size_t)(bm * 256 + r0_) * K + (c0_ >> 1);
  const unsigned short* gA1p = A + (size_t)(bm * 256 + r1_) * K + (c1_ >> 1);
  const unsigned short* gA2p = A + (size_t)(bm * 256 + r2_) * K + (c2_ >> 1);
  const unsigned short* gA3p = A + (size_t)(bm * 256 + r3_) * K + (c3_ >> 1);
  const unsigned short* gB0p = Bt + (size_t)(bn * 128 + r0_) * K + (c0_ >> 1);
  const unsigned short* gB1p = Bt + (size_t)(bn * 128 + r1_) * K + (c1_ >> 1);
  const int aL0 = L0 >> 1, aL1 = L1 >> 1, aL2 = L2 >> 1, aL3 = L3 >> 1;

  auto stageA0 = [&](int tt){ unsigned short* b = SA + (tt % 3) * 16384;
    gload16(gA0p + (size_t)tt * 64, b + aL0);
    gload16(gA1p + (size_t)tt * 64, b + aL1); };
  auto stageA1 = [&](int tt){ unsigned short* b = SA + (tt % 3) * 16384;
    gload16(gA2p + (size_t)tt * 64, b + aL2);
    gload16(gA3p + (size_t)tt * 64, b + aL3); };
  auto stageB = [&](int tt){ unsigned short* b = SB + (tt % 3) * 8192;
    gload16(gB0p + (size_t)tt * 64, b + aL0);
    gload16(gB1p + (size_t)tt * 64, b + aL1); };

  f32x4 acc[4][4];
  #pragma unroll
  for (int i = 0; i < 4; i++)
    #pragma unroll
    for (int j = 0; j < 4; j++) acc[i][j] = f32x4{0.f, 0.f, 0.f, 0.f};

  const int NT = K >> 6;
  // prologue: stage tiles 0 and 1 (6 loads each, in order)
  stageA0(0); stageA1(0); stageB(0);
  stageA0(1); stageA1(1); stageB(1);

  for (int t = 0; t < NT; ++t){
    // boundary: tile t resident for ALL waves; tile t+1's 6 loads may stay in flight
    if (t < NT - 1) asm volatile("s_waitcnt vmcnt(6)" ::: "memory");
    else            asm volatile("s_waitcnt vmcnt(0)" ::: "memory");
    __builtin_amdgcn_s_barrier();
    __builtin_amdgcn_sched_barrier(0);
    const unsigned short* as = SA + (t % 3) * 16384;
    const unsigned short* bs = SB + (t % 3) * 8192;
    const bool st = (t + 2 < NT);   // stage into slot (t+2)%3: its readers done at tile t-1
    bf16x8 a0, a1, a2, a3, b0, b1, b2, b3;

    // ---- phase 0: k-half 0, rows i=0,1 ----
    a0 = *(const bf16x8*)(as + aoff0);
    a1 = *(const bf16x8*)(as + aoff0 + 1024);
    b0 = *(const bf16x8*)(bs + boff0);
    b1 = *(const bf16x8*)(bs + boff0 + 1024);
    b2 = *(const bf16x8*)(bs + boff0 + 2048);
    b3 = *(const bf16x8*)(bs + boff0 + 3072);
    if (st) stageA0(t + 2);
    __builtin_amdgcn_s_barrier();
    asm volatile("s_waitcnt lgkmcnt(0)" ::: "memory");
    __builtin_amdgcn_sched_barrier(0);
    __builtin_amdgcn_s_setprio(1);
    acc[0][0] = MFMA_B16(a0, b0, acc[0][0]); acc[0][1] = MFMA_B16(a0, b1, acc[0][1]);
    acc[0][2] = MFMA_B16(a0, b2, acc[0][2]); acc[0][3] = MFMA_B16(a0, b3, acc[0][3]);
    acc[1][0] = MFMA_B16(a1, b0, acc[1][0]); acc[1][1] = MFMA_B16(a1, b1, acc[1][1]);
    acc[1][2] = MFMA_B16(a1, b2, acc[1][2]); acc[1][3] = MFMA_B16(a1, b3, acc[1][3]);
    __builtin_amdgcn_s_setprio(0);
    __builtin_amdgcn_s_barrier();

    // ---- phase 1: k-half 0, rows i=2,3 ----
    a2 = *(const bf16x8*)(as + aoff0 + 2048);
    a3 = *(const bf16x8*)(as + aoff0 + 3072);
    if (st) stageA1(t + 2);
    __builtin_amdgcn_s_barrier();
    asm volatile("s_waitcnt lgkmcnt(0)" ::: "memory");
    __builtin_amdgcn_sched_barrier(0);
    __builtin_amdgcn_s_setprio(1);
    acc[2][0] = MFMA_B16(a2, b0, acc[2][0]); acc[2][1] = MFMA_B16(a2, b1, acc[2][1]);
    acc[2][2] = MFMA_B16(a2, b2, acc[2][2]); acc[2][3] = MFMA_B16(a2, b3, acc[2][3]);
    acc[3][0] = MFMA_B16(a3, b0, acc[3][0]); acc[3][1] = MFMA_B16(a3, b1, acc[3][1]);
    acc[3][2] = MFMA_B16(a3, b2, acc[3][2]); acc[3][3] = MFMA_B16(a3, b3, acc[3][3]);
    __builtin_amdgcn_s_setprio(0);
    __builtin_amdgcn_s_barrier();

    // ---- phase 2: k-half 1, rows i=0,1 ----
    a0 = *(const bf16x8*)(as + aoff1);
    a1 = *(const bf16x8*)(as + aoff1 + 1024);
    b0 = *(const bf16x8*)(bs + boff1);
    b1 = *(const bf16x8*)(bs + boff1 + 1024);
    b2 = *(const bf16x8*)(bs + boff1 + 2048);
    b3 = *(const bf16x8*)(bs + boff1 + 3072);
    if (st) stageB(t + 2);
    __builtin_amdgcn_s_barrier();
    asm volatile("s_waitcnt lgkmcnt(0)" ::: "memory");
    __builtin_amdgcn_sched_barrier(0);
    __builtin_amdgcn_s_setprio(1);
    acc[0][0] = MFMA_B16(a0, b0, acc[0][0]); acc[0][1] = MFMA_B16(a0, b1, acc[0][1]);
    acc[0][2] = MFMA_B16(a0, b2, acc[0][2]); acc[0][3] = MFMA_B16(a0, b3, acc[0][3]);
    acc[1][0] = MFMA_B16(a1, b0, acc[1][0]); acc[1][1] = MFMA_B16(a1, b1, acc[1][1]);
    acc[1][2] = MFMA_B16(a1, b2, acc[1][2]); acc[1][3] = MFMA_B16(a1, b3, acc[1][3]);
    __builtin_amdgcn_s_setprio(0);
    __builtin_amdgcn_s_barrier();

    // ---- phase 3: k-half 1, rows i=2,3 (boundary supplies the closing barrier) ----
    a2 = *(const bf16x8*)(as + aoff1 + 2048);
    a3 = *(const bf16x8*)(as + aoff1 + 3072);
    __builtin_amdgcn_s_barrier();
    asm volatile("s_waitcnt lgkmcnt(0)" ::: "memory");
    __builtin_amdgcn_sched_barrier(0);
    __builtin_amdgcn_s_setprio(1);
    acc[2][0] = MFMA_B16(a2, b0, acc[2][0]); acc[2][1] = MFMA_B16(a2, b1, acc[2][1]);
    acc[2][2] = MFMA_B16(a2, b2, acc[2][2]); acc[2][3] = MFMA_B16(a2, b3, acc[2][3]);
    acc[3][0] = MFMA_B16(a3, b0, acc[3][0]); acc[3][1] = MFMA_B16(a3, b1, acc[3][1]);
    acc[3][2] = MFMA_B16(a3, b2, acc[3][2]); acc[3][3] = MFMA_B16(a3, b3, acc[3][3]);
    __builtin_amdgcn_s_setprio(0);
  }

  // ---- epilogue ----
  if (EPI == 1){
    const int colbase = bn * 128 + wcol * 64;
    if (bn < 32){
      // q/k: RoPE pre-rounding, write qk[row][col]
      #pragma unroll
      for (int i = 0; i < 4; i++){
        #pragma unroll
        for (int j = 0; j < 4; j++){
          int col = colbase + j * 16 + li;
          int ii = (col & 63) >> 1;
          #pragma unroll
          for (int r = 0; r < 4; r++){
            int row = bm * 256 + wrow * 64 + i * 16 + lg * 4 + r;
            int pos = row & (TT - 1);
            const float* tp = tab + ((size_t)pos * 32 + ii) * 2;
            float c = tp[0], s = tp[1];
            float val = acc[i][j][r];
            float pv = __shfl_xor(val, 1);
            float res = (li & 1) ? (pv * s + val * c) : (val * c - pv * s);
            qk[(size_t)row * 4096 + col] = f2bf(res);
          }
        }
      }
    } else {
      // v: write transposed vt[(b*32+h)*64+d][t0..t0+3]
      #pragma unroll
      for (int i = 0; i < 4; i++){
        #pragma unroll
        for (int j = 0; j < 4; j++){
          int vcol = colbase + j * 16 + li - 4096;
          int hh = vcol >> 6, d = vcol & 63;
          int row0 = bm * 256 + wrow * 64 + i * 16 + lg * 4;
          int b = row0 >> 10, t0 = row0 & (TT - 1);
          ushort4 pk;
          pk.x = f2bf(acc[i][j][0]); pk.y = f2bf(acc[i][j][1]);
          pk.z = f2bf(acc[i][j][2]); pk.w = f2bf(acc[i][j][3]);
          *(ushort4*)(vt + ((size_t)((b * 32 + hh) * 64 + d)) * TT + t0) = pk;
        }
      }
    }
  } else {
    #pragma unroll
    for (int i = 0; i < 4; i++)
      #pragma unroll
      for (int j = 0; j < 4; j++)
        #pragma unroll
        for (int r = 0; r < 4; r++){
          size_t row = (size_t)(bm * 256 + wrow * 64 + i * 16 + lg * 4 + r);
          size_t col = (size_t)(bn * 128 + wcol * 64 + j * 16 + li);
          Cf[row * N + col] = acc[i][j][r];
        }
  }
}

// ---------------- sparse flash attention over gathered active q rows ----------------
__global__ __launch_bounds__(256) void attn_sparse_kernel(const unsigned short* __restrict__ qk,
                                                          const unsigned short* __restrict__ vt,
                                                          const float* __restrict__ gate,
                                                          const int* __restrict__ idx,
                                                          const int* __restrict__ counts,
                                                          unsigned short* __restrict__ attn_out){
  __shared__ unsigned short Ks[64 * 64];
  __shared__ unsigned short Vs[64 * 64];
  __shared__ unsigned short Ps[4][16 * 64];
  const int bh = blockIdx.x, qt = blockIdx.y;
  const int count = counts[bh];
  if (qt * 64 >= count) return;
  const int b = bh >> 5, h = bh & 31;
  const int tid = threadIdx.x, lane = tid & 63, w = tid >> 6;
  const int li = lane & 15, lg = lane >> 4;
  const int* myidx = idx + bh * TT + qt * 64;
  const int nvalid = min(64, count - qt * 64);
  const int qmax = myidx[nvalid - 1];

  int qi[4];
  #pragma unroll
  for (int r = 0; r < 4; r++){
    int s = w * 16 + lg * 4 + r;
    qi[r] = (s < nvalid) ? myidx[s] : -1;
  }
  int qrow = (w * 16 + li < nvalid) ? myidx[w * 16 + li] : 0;
  bf16x8 qf0, qf1;
  {
    const unsigned short* qp = qk + (size_t)(b * TT + qrow) * 4096 + h * 64;
    qf0 = *(const bf16x8*)(qp + lg * 8);
    qf1 = *(const bf16x8*)(qp + 32 + lg * 8);
  }
  f32x4 o[4];
  #pragma unroll
  for (int i = 0; i < 4; i++) o[i] = f32x4{0.f, 0.f, 0.f, 0.f};
  float m_run[4], l_run[4];
  #pragma unroll
  for (int r = 0; r < 4; r++){ m_run[r] = -1e30f; l_run[r] = 0.f; }

  const int nkt = (qmax >> 6) + 1;
  for (int kt = 0; kt < nkt; kt++){
    const int kb = kt * 64;
    #pragma unroll
    for (int s2 = 0; s2 < 2; s2++){
      int s = s2 * 256 + tid;
      int r = s >> 3, c = (s & 7) * 8;
      gload16(qk + (size_t)(b * TT + kb + r) * 4096 + 2048 + h * 64 + c, &Ks[s * 8]);
      gload16(vt + (size_t)(bh * 64 + r) * TT + kb + c, &Vs[s * 8]);
    }
    __syncthreads();

    f32x4 s4[4];
    #pragma unroll
    for (int ni = 0; ni < 4; ni++){
      bf16x8 k0 = *(const bf16x8*)(&Ks[(ni * 16 + li) * 64 + lg * 8]);
      bf16x8 k1 = *(const bf16x8*)(&Ks[(ni * 16 + li) * 64 + 32 + lg * 8]);
      f32x4 t = f32x4{0.f, 0.f, 0.f, 0.f};
      t = MFMA_B16(qf0, k0, t);
      t = MFMA_B16(qf1, k1, t);
      s4[ni] = t;
    }
    float mt[4];
    #pragma unroll
    for (int r = 0; r < 4; r++) mt[r] = -1e30f;
    #pragma unroll
    for (int ni = 0; ni < 4; ni++){
      int kidx = kb + ni * 16 + li;
      #pragma unroll
      for (int r = 0; r < 4; r++){
        float val = s4[ni][r] * 0.125f;
        val = (kidx <= qi[r]) ? val : -1e30f;
        s4[ni][r] = val;
        mt[r] = fmaxf(mt[r], val);
      }
    }
    #pragma unroll
    for (int r = 0; r < 4; r++){
      #pragma unroll
      for (int sh = 8; sh >= 1; sh >>= 1) mt[r] = fmaxf(mt[r], __shfl_xor(mt[r], sh));
      float mnew = fmaxf(m_run[r], mt[r]);
      float corr = __expf(m_run[r] - mnew);
      m_run[r] = mnew;
      l_run[r] *= corr;
      #pragma unroll
      for (int j = 0; j < 4; j++) o[j][r] *= corr;
    }
    float rs[4] = {0.f, 0.f, 0.f, 0.f};
    #pragma unroll
    for (int ni = 0; ni < 4; ni++)
      #pragma unroll
      for (int r = 0; r < 4; r++){
        float p = __expf(s4[ni][r] - m_run[r]);
        s4[ni][r] = p;
        rs[r] += p;
      }
    #pragma unroll
    for (int r = 0; r < 4; r++){
      #pragma unroll
      for (int sh = 8; sh >= 1; sh >>= 1) rs[r] += __shfl_xor(rs[r], sh);
      l_run[r] += rs[r];
    }
    #pragma unroll
    for (int ni = 0; ni < 4; ni++)
      #pragma unroll
      for (int r = 0; r < 4; r++)
        Ps[w][(lg * 4 + r) * 64 + ni * 16 + li] = f2bf(s4[ni][r]);
    #pragma unroll
    for (int ks = 0; ks < 2; ks++){
      bf16x8 pa = *(const bf16x8*)(&Ps[w][li * 64 + ks * 32 + lg * 8]);
      #pragma unroll
      for (int ni = 0; ni < 4; ni++){
        bf16x8 vb = *(const bf16x8*)(&Vs[(ni * 16 + li) * 64 + ks * 32 + lg * 8]);
        o[ni] = MFMA_B16(pa, vb, o[ni]);
      }
    }
    __syncthreads();
  }
  #pragma unroll
  for (int r = 0; r < 4; r++){
    if (qi[r] < 0) continue;
    float g = gate[(size_t)(b * TT + qi[r]) * 32 + h];
    float inv = g / l_run[r];
    #pragma unroll
    for (int ni = 0; ni < 4; ni++)
      attn_out[(size_t)(b * TT + qi[r]) * 2048 + h * 64 + ni * 16 + li] = f2bf(o[ni][r] * inv);
  }
}

extern "C" void kernel_launch(void* const* d_in, const int* in_sizes, int n_in,
                              void* d_out, int out_size, void* d_ws, size_t ws_size,
                              hipStream_t stream){
  const float* x        = (const float*)d_in[0];
  const float* w_router = (const float*)d_in[1];
  const float* w_qkv    = (const float*)d_in[2];
  const float* w_out    = (const float*)d_in[3];
  float* out = (float*)d_out;
  char* ws = (char*)d_ws;

  unsigned short* qk    = (unsigned short*)(ws);                        // 33554432 B [4096][4096]
  unsigned short* vt    = (unsigned short*)(ws + 33554432);             // 16777216 B
  unsigned short* x_bf  = (unsigned short*)(ws + 50331648);             // 16777216 B
  unsigned short* wqkvT = (unsigned short*)(ws + 67108864);             // 25165824 B
  unsigned short* woutT = (unsigned short*)(ws + 92274688);             // 8388608 B
  float* gate           = (float*)(ws + 100663296);                     // 524288 B
  float* tab            = (float*)(ws + 101187584);                     // 262144 B
  unsigned short* attn  = x_bf;                      // reuse after qkv GEMM
  int* idx              = (int*)(ws + 67108864);     // reuse wqkvT region after qkv GEMM
  int* counts           = (int*)(ws + 67633152);

  constexpr int GEMM_LDS = 147456;  // 3 x (32KB A + 16KB B)
  (void)hipFuncSetAttribute(reinterpret_cast<const void*>(&gemm8<1>),
                            hipFuncAttributeMaxDynamicSharedMemorySize, GEMM_LDS);
  (void)hipFuncSetAttribute(reinterpret_cast<const void*>(&gemm8<0>),
                            hipFuncAttributeMaxDynamicSharedMemorySize, GEMM_LDS);

  hipLaunchKernelGGL(transpose_cast_kernel, dim3(192, 64), dim3(32, 8), 0, stream, w_qkv, wqkvT, 2048, 6144);
  hipLaunchKernelGGL(transpose_cast_kernel, dim3(64, 64), dim3(32, 8), 0, stream, w_out, woutT, 2048, 2048);
  hipLaunchKernelGGL(rope_table_kernel, dim3(128), dim3(256), 0, stream, tab);
  hipLaunchKernelGGL(prep_kernel, dim3(512), dim3(256), 0, stream, x, w_router, x_bf, gate);
  hipLaunchKernelGGL((gemm8<1>), dim3(768), dim3(512), GEMM_LDS, stream,
                     x_bf, wqkvT, (float*)nullptr, qk, vt, tab, 6144, 2048, 48);
  hipLaunchKernelGGL(compact_kernel, dim3(128), dim3(64), 0, stream, gate, idx, counts);
  (void)hipMemsetAsync(attn, 0, (size_t)4096 * 2048 * 2, stream);
  hipLaunchKernelGGL(attn_sparse_kernel, dim3(128, 16), dim3(256), 0, stream, qk, vt, gate, idx, counts, attn);
  hipLaunchKernelGGL((gemm8<0>), dim3(256), dim3(512), GEMM_LDS, stream,
                     attn, woutT, out, (unsigned short*)nullptr, (unsigned short*)nullptr,
                     (const float*)nullptr, 2048, 2048, 16);
}